// Round 1
// baseline (4035.667 us; speedup 1.0000x reference)
//
#include <hip/hip_runtime.h>
#include <hip/hip_bf16.h>
#include <math.h>

// Problem constants
#define DM 96
#define DI 192
#define DSTATE 64
#define NH 8
#define HD 24
#define CD 320
#define ZD 520
#define LSEQ 512
#define NSEQ 24            // B(2) * 12 directions
#define NROW (NSEQ*LSEQ)   // 12288

__device__ __forceinline__ float wave_sum64(float v){
  #pragma unroll
  for (int o = 32; o > 0; o >>= 1) v += __shfl_down(v, o);
  return v;
}

__device__ __forceinline__ float silu_f(float x){
  return x / (1.f + expf(-x));
}

// ---------------------------------------------------------------------------
// 1) downsample: pixel-unshuffle(2) -> LN(384) -> @ ds_red_w.T -> res[b,m,vox]
// grid = B*512 voxels, block = 128
__global__ void k_downsample(const float* __restrict__ x,
                             const float* __restrict__ lnw,
                             const float* __restrict__ lnb,
                             const float* __restrict__ redw,
                             float* __restrict__ res){
  int vox = blockIdx.x;          // b*512 + i*64+j*8+k
  int b = vox >> 9; int r = vox & 511;
  int i = r >> 6, j = (r >> 3) & 7, k = r & 7;
  __shared__ float t[384];
  __shared__ float sm[4];
  int tid = threadIdx.x;
  for (int f = tid; f < 384; f += 128){
    int c = f >> 3; int di = (f >> 2) & 1, dj = (f >> 1) & 1, dk = f & 1;
    int X = 2*i + di, Y = 2*j + dj, Z = 2*k + dk;
    t[f] = x[(((b*48 + c)*16 + X)*16 + Y)*16 + Z];
  }
  __syncthreads();
  float s = 0.f, s2 = 0.f;
  for (int f = tid; f < 384; f += 128){ float v = t[f]; s += v; s2 += v*v; }
  s = wave_sum64(s); s2 = wave_sum64(s2);
  int lane = tid & 63, wv = tid >> 6;
  if (lane == 0){ sm[wv] = s; sm[2+wv] = s2; }
  __syncthreads();
  float mean = (sm[0] + sm[1]) * (1.f/384.f);
  float var  = (sm[2] + sm[3]) * (1.f/384.f) - mean*mean;
  float rstd = rsqrtf(var + 1e-5f);
  __syncthreads();
  for (int f = tid; f < 384; f += 128) t[f] = (t[f]-mean)*rstd*lnw[f] + lnb[f];
  __syncthreads();
  if (tid < 96){
    const float* wrow = redw + tid*384;
    float acc = 0.f;
    #pragma unroll 4
    for (int f = 0; f < 384; f++) acc = fmaf(t[f], wrow[f], acc);
    res[((b*96 + tid)*512) + r] = acc;
  }
}

// ---------------------------------------------------------------------------
// 2) build the 24 sequences: H[s, t, m]
__global__ void k_build_hs(const float* __restrict__ res, float* __restrict__ H){
  int idx = blockIdx.x*blockDim.x + threadIdx.x;
  if (idx >= NSEQ*LSEQ*DM) return;
  int m = idx % DM; int t = (idx/DM) % LSEQ; int s = idx/(DM*LSEQ);
  int b = s / 12, d = s % 12;
  int tt = (d & 2) ? (511 - t) : t;
  int a = tt >> 6, bb = (tt >> 3) & 7, cc = tt & 7;
  int i, j, k;
  int g = d >> 2; bool sw = d & 1;
  if (g == 0){ if (!sw){ i=a; j=bb; k=cc; } else { i=a; k=bb; j=cc; } }
  else if (g == 1){ if (!sw){ j=a; k=bb; i=cc; } else { j=a; i=bb; k=cc; } }
  else { if (!sw){ k=a; i=bb; j=cc; } else { k=a; j=bb; i=cc; } }
  H[idx] = res[((b*96 + m)*512) + (i*64 + j*8 + k)];
}

// ---------------------------------------------------------------------------
// 3) fused (optional add) + LayerNorm over 96.  grid = NROW, block = 128
//    Rout (optional) gets A(+B); U gets LN(A(+B))*w+b
__global__ void k_add_ln(const float* __restrict__ A, const float* __restrict__ Bp,
                         float* __restrict__ Rout, float* __restrict__ U,
                         const float* __restrict__ w, const float* __restrict__ bias){
  int row = blockIdx.x; int tid = threadIdx.x;
  float v = 0.f;
  if (tid < DM){
    v = A[row*DM + tid];
    if (Bp) v += Bp[row*DM + tid];
  }
  float s = wave_sum64(v), s2 = wave_sum64(v*v);
  __shared__ float sm[4];
  int lane = tid & 63, wv = tid >> 6;
  if (lane == 0){ sm[wv] = s; sm[2+wv] = s2; }
  __syncthreads();
  float mean = (sm[0] + sm[1]) * (1.f/96.f);
  float var  = (sm[2] + sm[3]) * (1.f/96.f) - mean*mean;
  float rstd = rsqrtf(var + 1e-5f);
  if (tid < DM){
    if (Rout) Rout[row*DM + tid] = v;
    U[row*DM + tid] = (v-mean)*rstd*w[tid] + bias[tid];
  }
}

// ---------------------------------------------------------------------------
// 4) generic row GEMM: C[row, n] = act(A[row,:K] . W[n,:K] + bias[n]) (+C if beta)
//    grid = M rows, block = 256, dyn LDS = K floats
template<int ACT>   // 0 = none, 1 = gelu(exact)
__global__ void k_gemm(const float* __restrict__ A, const float* __restrict__ W,
                       const float* __restrict__ bias, float* __restrict__ C,
                       int N, int K, int beta){
  int row = blockIdx.x;
  extern __shared__ float aRow[];
  for (int k = threadIdx.x; k < K; k += blockDim.x) aRow[k] = A[row*K + k];
  __syncthreads();
  for (int n = threadIdx.x; n < N; n += blockDim.x){
    const float* wn = W + n*K;
    float acc = 0.f;
    #pragma unroll 4
    for (int k = 0; k < K; k++) acc = fmaf(aRow[k], wn[k], acc);
    if (bias) acc += bias[n];
    if (ACT == 1) acc = 0.5f*acc*(1.f + erff(acc*0.70710678118654752f));
    float out = beta ? (C[row*N + n] + acc) : acc;
    C[row*N + n] = out;
  }
}

// ---------------------------------------------------------------------------
// 5) causal conv (4 taps) + bias + silu over the 320 xBC channels
__global__ void k_conv(const float* __restrict__ ZX, const float* __restrict__ cw,
                       const float* __restrict__ cb, float* __restrict__ XBC){
  int idx = blockIdx.x*blockDim.x + threadIdx.x;
  if (idx >= NSEQ*LSEQ*CD) return;
  int c = idx % CD; int t = (idx/CD) % LSEQ; int s = idx/(CD*LSEQ);
  float acc = cb[c];
  #pragma unroll
  for (int k = 0; k < 4; k++){
    int tt = t - 3 + k;
    if (tt >= 0) acc = fmaf(ZX[(s*LSEQ + tt)*ZD + DI + c], cw[c*4 + k], acc);
  }
  XBC[idx] = silu_f(acc);
}

// 6) dt = softplus(raw + bias); dA = exp(-exp(A_log)*dt)
__global__ void k_dt(const float* __restrict__ ZX, const float* __restrict__ dtb,
                     const float* __restrict__ alog, float* __restrict__ DT,
                     float* __restrict__ DA){
  int idx = blockIdx.x*blockDim.x + threadIdx.x;
  if (idx >= NSEQ*LSEQ*NH) return;
  int h = idx % NH; int row = idx / NH;
  float xr = ZX[row*ZD + 512 + h] + dtb[h];
  float dt = (xr > 20.f) ? xr : log1pf(expf(xr));
  DT[idx] = dt;
  DA[idx] = expf(-expf(alog[h]) * dt);
}

// ---------------------------------------------------------------------------
// 7) sequential SSM scan. grid = NSEQ*NH blocks, block = 256 (4 waves x 64 lanes)
//    lane = state col n; wave w owns head-dim rows p = w*6 + q (q<6)
__global__ void k_scan(const float* __restrict__ XBC, const float* __restrict__ DT,
                       const float* __restrict__ DA, const float* __restrict__ Dv,
                       float* __restrict__ Y){
  int s = blockIdx.x >> 3; int h = blockIdx.x & 7;
  int lane = threadIdx.x & 63; int wv = threadIdx.x >> 6;
  float hreg[6] = {0.f,0.f,0.f,0.f,0.f,0.f};
  const float* xb = XBC + (size_t)s*LSEQ*CD;
  float dcoef = Dv[h];
  for (int t = 0; t < LSEQ; t++){
    const float* xt = xb + t*CD;
    float dAv = DA[(s*LSEQ + t)*NH + h];
    float dtv = DT[(s*LSEQ + t)*NH + h];
    float Bv = xt[DI + lane];
    float Cv = xt[DI + DSTATE + lane];
    #pragma unroll
    for (int q = 0; q < 6; q++){
      int p = wv*6 + q;
      float xh = xt[h*HD + p];
      hreg[q] = fmaf(dAv, hreg[q], dtv*xh*Bv);
      float contrib = wave_sum64(hreg[q]*Cv);
      if (lane == 0) Y[((size_t)(s*LSEQ + t))*DI + h*HD + p] = contrib + dcoef*xh;
    }
  }
}

// ---------------------------------------------------------------------------
// 8) gate with silu(z) + RMSNorm(192) * nw  (in place on Y)
__global__ void k_gate(float* __restrict__ Y, const float* __restrict__ ZX,
                       const float* __restrict__ nw){
  int row = blockIdx.x; int tid = threadIdx.x;
  float y = 0.f;
  if (tid < DI){
    float z = ZX[(size_t)row*ZD + tid];
    y = Y[(size_t)row*DI + tid] * silu_f(z);
  }
  float s2 = wave_sum64(y*y);
  __shared__ float sm[4];
  int lane = tid & 63, wv = tid >> 6;
  if (lane == 0) sm[wv] = s2;
  __syncthreads();
  float rms = rsqrtf((sm[0]+sm[1]+sm[2]+sm[3]) * (1.f/192.f) + 1e-5f);
  if (tid < DI) Y[(size_t)row*DI + tid] = y * rms * nw[tid];
}

// ---------------------------------------------------------------------------
// 9) merge 12 directions -> output (B, 96, 8, 8, 8)
__global__ void k_merge(const float* __restrict__ F, float* __restrict__ out){
  int idx = blockIdx.x*blockDim.x + threadIdx.x;
  if (idx >= 2*96*512) return;
  int r = idx % 512; int m = (idx/512) % 96; int b = idx/(512*96);
  int i = r >> 6, j = (r >> 3) & 7, k = r & 7;
  int ti = r;
  int tj = j*64 + k*8 + i;
  int tk = k*64 + i*8 + j;
  const float* Fb = F + (size_t)(b*12)*LSEQ*DM;
  float acc = 0.f;
  acc += Fb[(0*LSEQ + ti)*DM + m]        + Fb[(1*LSEQ + ti)*DM + m];
  acc += Fb[(2*LSEQ + (511-ti))*DM + m]  + Fb[(3*LSEQ + (511-ti))*DM + m];
  acc += Fb[(4*LSEQ + tj)*DM + m]        + Fb[(5*LSEQ + tj)*DM + m];
  acc += Fb[(6*LSEQ + (511-tj))*DM + m]  + Fb[(7*LSEQ + (511-tj))*DM + m];
  acc += Fb[(8*LSEQ + tk)*DM + m]        + Fb[(9*LSEQ + tk)*DM + m];
  acc += Fb[(10*LSEQ + (511-tk))*DM + m] + Fb[(11*LSEQ + (511-tk))*DM + m];
  out[idx] = acc * (1.f/12.f);
}

// ---------------------------------------------------------------------------
extern "C" void kernel_launch(void* const* d_in, const int* in_sizes, int n_in,
                              void* d_out, int out_size, void* d_ws, size_t ws_size,
                              hipStream_t stream){
  const float* x        = (const float*)d_in[0];
  const float* ds_ln_w  = (const float*)d_in[1];
  const float* ds_ln_b  = (const float*)d_in[2];
  const float* ds_red_w = (const float*)d_in[3];
  const float* norm1_w  = (const float*)d_in[4];
  const float* norm1_b  = (const float*)d_in[5];
  const float* in_proj_w= (const float*)d_in[6];
  const float* conv_w   = (const float*)d_in[7];
  const float* conv_b   = (const float*)d_in[8];
  const float* dt_bias  = (const float*)d_in[9];
  const float* A_log    = (const float*)d_in[10];
  const float* Dv       = (const float*)d_in[11];
  const float* ssm_nw   = (const float*)d_in[12];
  const float* out_pw   = (const float*)d_in[13];
  const float* norm2_w  = (const float*)d_in[14];
  const float* norm2_b  = (const float*)d_in[15];
  const float* fc1_w    = (const float*)d_in[16];
  const float* fc1_b    = (const float*)d_in[17];
  const float* fc2_w    = (const float*)d_in[18];
  const float* fc2_b    = (const float*)d_in[19];
  const float* normf_w  = (const float*)d_in[20];
  const float* normf_b  = (const float*)d_in[21];
  float* out = (float*)d_out;

  float* ws = (float*)d_ws;
  const size_t NRES = 2*96*512;             // 98304
  const size_t NHS  = (size_t)NROW*DM;      // 1179648
  const size_t NZX  = (size_t)NROW*ZD;      // 6389760
  const size_t NXBC = (size_t)NROW*CD;      // 3932160
  const size_t NDT  = (size_t)NROW*NH;      // 98304
  float* res = ws;
  float* H   = res + NRES;
  float* R   = H + NHS;
  float* U   = R + NHS;
  float* ZX  = U + NHS;
  float* XBC = ZX + NZX;
  float* DT  = XBC + NXBC;
  float* DA  = DT + NDT;
  float* Y   = DA + NDT;
  float* T1  = XBC;   // alias: XBC dead once fc1 runs

  k_downsample<<<2*512, 128, 0, stream>>>(x, ds_ln_w, ds_ln_b, ds_red_w, res);
  k_build_hs<<<(NSEQ*LSEQ*DM + 255)/256, 256, 0, stream>>>(res, H);

  for (int l = 0; l < 2; l++){
    const float* n1w = norm1_w + l*DM,  * n1b = norm1_b + l*DM;
    const float* ipw = in_proj_w + (size_t)l*ZD*DM;
    const float* cw  = conv_w + (size_t)l*CD*4, * cb = conv_b + (size_t)l*CD;
    const float* dtb = dt_bias + l*NH, * alog = A_log + l*NH, * dvl = Dv + l*NH;
    const float* snw = ssm_nw + (size_t)l*DI;
    const float* opw = out_pw + (size_t)l*DM*DI;
    const float* n2w = norm2_w + l*DM,  * n2b = norm2_b + l*DM;
    const float* f1w = fc1_w + (size_t)l*DI*DM, * f1b = fc1_b + (size_t)l*DI;
    const float* f2w = fc2_w + (size_t)l*DM*DI, * f2b = fc2_b + (size_t)l*DM;

    // residual = hs (+ old residual); u = LN1(residual)
    k_add_ln<<<NROW, 128, 0, stream>>>(H, l == 0 ? nullptr : R, R, U, n1w, n1b);
    // zxbcdt = u @ in_proj.T
    k_gemm<0><<<NROW, 256, DM*sizeof(float), stream>>>(U, ipw, nullptr, ZX, ZD, DM, 0);
    // conv + silu ; dt/dA
    k_conv<<<(NSEQ*LSEQ*CD + 255)/256, 256, 0, stream>>>(ZX, cw, cb, XBC);
    k_dt<<<(NSEQ*LSEQ*NH + 255)/256, 256, 0, stream>>>(ZX, dtb, alog, DT, DA);
    // sequential scan (+ D*xh)
    k_scan<<<NSEQ*NH, 256, 0, stream>>>(XBC, DT, DA, dvl, Y);
    // gate + RMSNorm
    k_gate<<<NROW, 256, 0, stream>>>(Y, ZX, snw);
    // residual += y @ out_proj.T
    k_gemm<0><<<NROW, 256, DI*sizeof(float), stream>>>(Y, opw, nullptr, R, DM, DI, 1);
    // u = LN2(residual)
    k_add_ln<<<NROW, 128, 0, stream>>>(R, nullptr, nullptr, U, n2w, n2b);
    // MLP
    k_gemm<1><<<NROW, 256, DM*sizeof(float), stream>>>(U, f1w, f1b, T1, DI, DM, 0);
    k_gemm<0><<<NROW, 256, DI*sizeof(float), stream>>>(T1, f2w, f2b, H, DM, DI, 0);
  }

  // final = LN_f(hs + residual)
  k_add_ln<<<NROW, 128, 0, stream>>>(H, R, nullptr, U, normf_w, normf_b);
  k_merge<<<(2*96*512 + 255)/256, 256, 0, stream>>>(U, out);
}

// Round 2
// 2315.441 us; speedup vs baseline: 1.7429x; 1.7429x over previous
//
#include <hip/hip_runtime.h>
#include <hip/hip_bf16.h>
#include <math.h>

// Problem constants
#define DM 96
#define DI 192
#define DSTATE 64
#define NH 8
#define HD 24
#define CD 320
#define ZD 520
#define LSEQ 512
#define NSEQ 24            // B(2) * 12 directions
#define NROW (NSEQ*LSEQ)   // 12288

__device__ __forceinline__ float wave_sum64(float v){
  #pragma unroll
  for (int o = 32; o > 0; o >>= 1) v += __shfl_down(v, o);
  return v;
}

__device__ __forceinline__ float silu_f(float x){
  return x / (1.f + expf(-x));
}

// ---------------------------------------------------------------------------
// 1) downsample: pixel-unshuffle(2) -> LN(384) -> @ ds_red_w.T -> res[b,m,vox]
__global__ void k_downsample(const float* __restrict__ x,
                             const float* __restrict__ lnw,
                             const float* __restrict__ lnb,
                             const float* __restrict__ redw,
                             float* __restrict__ res){
  int vox = blockIdx.x;          // b*512 + i*64+j*8+k
  int b = vox >> 9; int r = vox & 511;
  int i = r >> 6, j = (r >> 3) & 7, k = r & 7;
  __shared__ float t[384];
  __shared__ float sm[4];
  int tid = threadIdx.x;
  for (int f = tid; f < 384; f += 128){
    int c = f >> 3; int di = (f >> 2) & 1, dj = (f >> 1) & 1, dk = f & 1;
    int X = 2*i + di, Y = 2*j + dj, Z = 2*k + dk;
    t[f] = x[(((b*48 + c)*16 + X)*16 + Y)*16 + Z];
  }
  __syncthreads();
  float s = 0.f, s2 = 0.f;
  for (int f = tid; f < 384; f += 128){ float v = t[f]; s += v; s2 += v*v; }
  s = wave_sum64(s); s2 = wave_sum64(s2);
  int lane = tid & 63, wv = tid >> 6;
  if (lane == 0){ sm[wv] = s; sm[2+wv] = s2; }
  __syncthreads();
  float mean = (sm[0] + sm[1]) * (1.f/384.f);
  float var  = (sm[2] + sm[3]) * (1.f/384.f) - mean*mean;
  float rstd = rsqrtf(var + 1e-5f);
  __syncthreads();
  for (int f = tid; f < 384; f += 128) t[f] = (t[f]-mean)*rstd*lnw[f] + lnb[f];
  __syncthreads();
  if (tid < 96){
    const float* wrow = redw + tid*384;
    float acc = 0.f;
    #pragma unroll 4
    for (int f = 0; f < 384; f++) acc = fmaf(t[f], wrow[f], acc);
    res[((b*96 + tid)*512) + r] = acc;
  }
}

// ---------------------------------------------------------------------------
// 2) build the 24 sequences: H[s, t, m]
__global__ void k_build_hs(const float* __restrict__ res, float* __restrict__ H){
  int idx = blockIdx.x*blockDim.x + threadIdx.x;
  if (idx >= NSEQ*LSEQ*DM) return;
  int m = idx % DM; int t = (idx/DM) % LSEQ; int s = idx/(DM*LSEQ);
  int b = s / 12, d = s % 12;
  int tt = (d & 2) ? (511 - t) : t;
  int a = tt >> 6, bb = (tt >> 3) & 7, cc = tt & 7;
  int i, j, k;
  int g = d >> 2; bool sw = d & 1;
  if (g == 0){ if (!sw){ i=a; j=bb; k=cc; } else { i=a; k=bb; j=cc; } }
  else if (g == 1){ if (!sw){ j=a; k=bb; i=cc; } else { j=a; i=bb; k=cc; } }
  else { if (!sw){ k=a; i=bb; j=cc; } else { k=a; j=bb; i=cc; } }
  H[idx] = res[((b*96 + m)*512) + (i*64 + j*8 + k)];
}

// ---------------------------------------------------------------------------
// 3) fused (optional add) + LayerNorm over 96
__global__ void k_add_ln(const float* __restrict__ A, const float* __restrict__ Bp,
                         float* __restrict__ Rout, float* __restrict__ U,
                         const float* __restrict__ w, const float* __restrict__ bias){
  int row = blockIdx.x; int tid = threadIdx.x;
  float v = 0.f;
  if (tid < DM){
    v = A[row*DM + tid];
    if (Bp) v += Bp[row*DM + tid];
  }
  float s = wave_sum64(v), s2 = wave_sum64(v*v);
  __shared__ float sm[4];
  int lane = tid & 63, wv = tid >> 6;
  if (lane == 0){ sm[wv] = s; sm[2+wv] = s2; }
  __syncthreads();
  float mean = (sm[0] + sm[1]) * (1.f/96.f);
  float var  = (sm[2] + sm[3]) * (1.f/96.f) - mean*mean;
  float rstd = rsqrtf(var + 1e-5f);
  if (tid < DM){
    if (Rout) Rout[row*DM + tid] = v;
    U[row*DM + tid] = (v-mean)*rstd*w[tid] + bias[tid];
  }
}

// ---------------------------------------------------------------------------
// 4) generic row GEMM
template<int ACT>   // 0 = none, 1 = gelu(exact)
__global__ void k_gemm(const float* __restrict__ A, const float* __restrict__ W,
                       const float* __restrict__ bias, float* __restrict__ C,
                       int N, int K, int beta){
  int row = blockIdx.x;
  extern __shared__ float aRow[];
  for (int k = threadIdx.x; k < K; k += blockDim.x) aRow[k] = A[row*K + k];
  __syncthreads();
  for (int n = threadIdx.x; n < N; n += blockDim.x){
    const float* wn = W + n*K;
    float acc = 0.f;
    #pragma unroll 4
    for (int k = 0; k < K; k++) acc = fmaf(aRow[k], wn[k], acc);
    if (bias) acc += bias[n];
    if (ACT == 1) acc = 0.5f*acc*(1.f + erff(acc*0.70710678118654752f));
    float out = beta ? (C[row*N + n] + acc) : acc;
    C[row*N + n] = out;
  }
}

// ---------------------------------------------------------------------------
// 5) causal conv (4 taps) + bias + silu
__global__ void k_conv(const float* __restrict__ ZX, const float* __restrict__ cw,
                       const float* __restrict__ cb, float* __restrict__ XBC){
  int idx = blockIdx.x*blockDim.x + threadIdx.x;
  if (idx >= NSEQ*LSEQ*CD) return;
  int c = idx % CD; int t = (idx/CD) % LSEQ; int s = idx/(CD*LSEQ);
  float acc = cb[c];
  #pragma unroll
  for (int k = 0; k < 4; k++){
    int tt = t - 3 + k;
    if (tt >= 0) acc = fmaf(ZX[(s*LSEQ + tt)*ZD + DI + c], cw[c*4 + k], acc);
  }
  XBC[idx] = silu_f(acc);
}

// 6) dt = softplus(raw + bias); dA = exp(-exp(A_log)*dt)
__global__ void k_dt(const float* __restrict__ ZX, const float* __restrict__ dtb,
                     const float* __restrict__ alog, float* __restrict__ DT,
                     float* __restrict__ DA){
  int idx = blockIdx.x*blockDim.x + threadIdx.x;
  if (idx >= NSEQ*LSEQ*NH) return;
  int h = idx % NH; int row = idx / NH;
  float xr = ZX[row*ZD + 512 + h] + dtb[h];
  float dt = (xr > 20.f) ? xr : log1pf(expf(xr));
  DT[idx] = dt;
  DA[idx] = expf(-expf(alog[h]) * dt);
}

// ---------------------------------------------------------------------------
// 7) SSM scan v2: grid = NSEQ*4 (4-way state split), block = 192.
//    thread = (p_grp: 4 head-dims, n_sub: 4 state cols). h[4][4] in regs.
//    y-reduce over n_sub = shfl_xor 1,2. Partials summed in k_gate2.
__global__ __launch_bounds__(192)
void k_scan2(const float* __restrict__ XBC, const float* __restrict__ DT,
             const float* __restrict__ DA, float* __restrict__ Y,
             float* __restrict__ YP3){
  int s = blockIdx.x >> 2;
  int nblk = blockIdx.x & 3;
  int tid = threadIdx.x;
  int n_sub = tid & 3;
  int p_grp = tid >> 2;       // 0..47
  int pp = p_grp * 4;         // flat head-dim 0..191 (4 per thread)
  int h = p_grp / 6;          // 6 p_grps per head
  int n0 = nblk*16 + n_sub*4; // 4 state cols per thread

  __shared__ float sDT[4096];
  __shared__ float sDA[4096];
  {
    const float4* s1 = (const float4*)(DT + (size_t)s*4096);
    const float4* s2 = (const float4*)(DA + (size_t)s*4096);
    float4* d1 = (float4*)sDT; float4* d2 = (float4*)sDA;
    for (int i = tid; i < 1024; i += 192){ d1[i] = s1[i]; d2[i] = s2[i]; }
  }
  __syncthreads();

  const float* xb = XBC + (size_t)s*LSEQ*CD;
  float* dst = (nblk == 0) ? Y : (YP3 + (size_t)(nblk-1)*NROW*DI);
  float* yout = dst + (size_t)s*LSEQ*DI + pp;

  float hr[4][4] = {{0.f}};
  // software pipeline, depth 2
  float4 xA = *(const float4*)(xb + pp);
  float4 bA = *(const float4*)(xb + 192 + n0);
  float4 cA = *(const float4*)(xb + 256 + n0);
  float4 xB = *(const float4*)(xb + CD + pp);
  float4 bB = *(const float4*)(xb + CD + 192 + n0);
  float4 cB = *(const float4*)(xb + CD + 256 + n0);

  for (int t = 0; t < LSEQ; ++t){
    int tn = (t + 2 < LSEQ) ? t + 2 : (LSEQ - 1);
    const float* bn = xb + (size_t)tn*CD;
    float4 xN = *(const float4*)(bn + pp);
    float4 bN = *(const float4*)(bn + 192 + n0);
    float4 cN = *(const float4*)(bn + 256 + n0);

    float dAv = sDA[t*8 + h];
    float dtv = sDT[t*8 + h];
    float xq[4] = {xA.x, xA.y, xA.z, xA.w};
    float Bn[4] = {bA.x, bA.y, bA.z, bA.w};
    float Cn[4] = {cA.x, cA.y, cA.z, cA.w};
    float y4[4];
    #pragma unroll
    for (int q = 0; q < 4; ++q){
      float dtx = dtv * xq[q];
      float acc = 0.f;
      #pragma unroll
      for (int n = 0; n < 4; ++n){
        hr[q][n] = fmaf(dAv, hr[q][n], dtx * Bn[n]);
        acc = fmaf(hr[q][n], Cn[n], acc);
      }
      acc += __shfl_xor(acc, 1);
      acc += __shfl_xor(acc, 2);
      y4[q] = acc;
    }
    if (n_sub == 0)
      *(float4*)(yout + (size_t)t*DI) = make_float4(y4[0], y4[1], y4[2], y4[3]);
    xA=xB; bA=bB; cA=cB; xB=xN; bB=bN; cB=cN;
  }
}

// ---------------------------------------------------------------------------
// 8) combine partials + D*xh + silu(z) gate + RMSNorm(192).  In-place on Y.
__global__ __launch_bounds__(192)
void k_gate2(float* __restrict__ Y, const float* __restrict__ YP3,
             const float* __restrict__ XBC, const float* __restrict__ ZX,
             const float* __restrict__ Dv, const float* __restrict__ nw){
  int row = blockIdx.x; int tid = threadIdx.x;
  size_t o = (size_t)row*DI + tid;
  const size_t PS = (size_t)NROW*DI;
  float y = Y[o] + YP3[o] + YP3[PS + o] + YP3[2*PS + o];
  int h = tid / 24;
  float xh = XBC[(size_t)row*CD + tid];
  y += Dv[h] * xh;
  float z = ZX[(size_t)row*ZD + tid];
  y *= silu_f(z);
  float s2 = wave_sum64(y*y);
  __shared__ float sm[3];
  int lane = tid & 63, wv = tid >> 6;
  if (lane == 0) sm[wv] = s2;
  __syncthreads();
  float rms = rsqrtf((sm[0]+sm[1]+sm[2]) * (1.f/192.f) + 1e-5f);
  Y[o] = y * rms * nw[tid];
}

// ---------------------------------------------------------------------------
// 9) merge 12 directions -> output
__global__ void k_merge(const float* __restrict__ F, float* __restrict__ out){
  int idx = blockIdx.x*blockDim.x + threadIdx.x;
  if (idx >= 2*96*512) return;
  int r = idx % 512; int m = (idx/512) % 96; int b = idx/(512*96);
  int i = r >> 6, j = (r >> 3) & 7, k = r & 7;
  int ti = r;
  int tj = j*64 + k*8 + i;
  int tk = k*64 + i*8 + j;
  const float* Fb = F + (size_t)(b*12)*LSEQ*DM;
  float acc = 0.f;
  acc += Fb[(0*LSEQ + ti)*DM + m]        + Fb[(1*LSEQ + ti)*DM + m];
  acc += Fb[(2*LSEQ + (511-ti))*DM + m]  + Fb[(3*LSEQ + (511-ti))*DM + m];
  acc += Fb[(4*LSEQ + tj)*DM + m]        + Fb[(5*LSEQ + tj)*DM + m];
  acc += Fb[(6*LSEQ + (511-tj))*DM + m]  + Fb[(7*LSEQ + (511-tj))*DM + m];
  acc += Fb[(8*LSEQ + tk)*DM + m]        + Fb[(9*LSEQ + tk)*DM + m];
  acc += Fb[(10*LSEQ + (511-tk))*DM + m] + Fb[(11*LSEQ + (511-tk))*DM + m];
  out[idx] = acc * (1.f/12.f);
}

// ---------------------------------------------------------------------------
extern "C" void kernel_launch(void* const* d_in, const int* in_sizes, int n_in,
                              void* d_out, int out_size, void* d_ws, size_t ws_size,
                              hipStream_t stream){
  const float* x        = (const float*)d_in[0];
  const float* ds_ln_w  = (const float*)d_in[1];
  const float* ds_ln_b  = (const float*)d_in[2];
  const float* ds_red_w = (const float*)d_in[3];
  const float* norm1_w  = (const float*)d_in[4];
  const float* norm1_b  = (const float*)d_in[5];
  const float* in_proj_w= (const float*)d_in[6];
  const float* conv_w   = (const float*)d_in[7];
  const float* conv_b   = (const float*)d_in[8];
  const float* dt_bias  = (const float*)d_in[9];
  const float* A_log    = (const float*)d_in[10];
  const float* Dv       = (const float*)d_in[11];
  const float* ssm_nw   = (const float*)d_in[12];
  const float* out_pw   = (const float*)d_in[13];
  const float* norm2_w  = (const float*)d_in[14];
  const float* norm2_b  = (const float*)d_in[15];
  const float* fc1_w    = (const float*)d_in[16];
  const float* fc1_b    = (const float*)d_in[17];
  const float* fc2_w    = (const float*)d_in[18];
  const float* fc2_b    = (const float*)d_in[19];
  const float* normf_w  = (const float*)d_in[20];
  const float* normf_b  = (const float*)d_in[21];
  float* out = (float*)d_out;

  float* ws = (float*)d_ws;
  const size_t NRES = 2*96*512;
  const size_t NHS  = (size_t)NROW*DM;
  const size_t NZX  = (size_t)NROW*ZD;
  const size_t NXBC = (size_t)NROW*CD;
  const size_t NDT  = (size_t)NROW*NH;
  const size_t NY   = (size_t)NROW*DI;
  float* res = ws;
  float* H   = res + NRES;
  float* R   = H + NHS;
  float* U   = R + NHS;
  float* ZX  = U + NHS;
  float* XBC = ZX + NZX;
  float* DT  = XBC + NXBC;
  float* DA  = DT + NDT;
  float* Y   = DA + NDT;
  float* YP3 = Y + NY;          // 3 extra scan partials
  float* T1  = XBC;             // alias: XBC dead once fc1 runs

  k_downsample<<<2*512, 128, 0, stream>>>(x, ds_ln_w, ds_ln_b, ds_red_w, res);
  k_build_hs<<<(NSEQ*LSEQ*DM + 255)/256, 256, 0, stream>>>(res, H);

  for (int l = 0; l < 2; l++){
    const float* n1w = norm1_w + l*DM,  * n1b = norm1_b + l*DM;
    const float* ipw = in_proj_w + (size_t)l*ZD*DM;
    const float* cw  = conv_w + (size_t)l*CD*4, * cb = conv_b + (size_t)l*CD;
    const float* dtb = dt_bias + l*NH, * alog = A_log + l*NH, * dvl = Dv + l*NH;
    const float* snw = ssm_nw + (size_t)l*DI;
    const float* opw = out_pw + (size_t)l*DM*DI;
    const float* n2w = norm2_w + l*DM,  * n2b = norm2_b + l*DM;
    const float* f1w = fc1_w + (size_t)l*DI*DM, * f1b = fc1_b + (size_t)l*DI;
    const float* f2w = fc2_w + (size_t)l*DM*DI, * f2b = fc2_b + (size_t)l*DM;

    k_add_ln<<<NROW, 128, 0, stream>>>(H, l == 0 ? nullptr : R, R, U, n1w, n1b);
    k_gemm<0><<<NROW, 256, DM*sizeof(float), stream>>>(U, ipw, nullptr, ZX, ZD, DM, 0);
    k_conv<<<(NSEQ*LSEQ*CD + 255)/256, 256, 0, stream>>>(ZX, cw, cb, XBC);
    k_dt<<<(NSEQ*LSEQ*NH + 255)/256, 256, 0, stream>>>(ZX, dtb, alog, DT, DA);
    k_scan2<<<NSEQ*4, 192, 0, stream>>>(XBC, DT, DA, Y, YP3);
    k_gate2<<<NROW, 192, 0, stream>>>(Y, YP3, XBC, ZX, dvl, snw);
    k_gemm<0><<<NROW, 256, DI*sizeof(float), stream>>>(Y, opw, nullptr, R, DM, DI, 1);
    k_add_ln<<<NROW, 128, 0, stream>>>(R, nullptr, nullptr, U, n2w, n2b);
    k_gemm<1><<<NROW, 256, DM*sizeof(float), stream>>>(U, f1w, f1b, T1, DI, DM, 0);
    k_gemm<0><<<NROW, 256, DI*sizeof(float), stream>>>(T1, f2w, f2b, H, DM, DI, 0);
  }

  k_add_ln<<<NROW, 128, 0, stream>>>(H, R, nullptr, U, normf_w, normf_b);
  k_merge<<<(2*96*512 + 255)/256, 256, 0, stream>>>(U, out);
}

// Round 3
// 806.566 us; speedup vs baseline: 5.0035x; 2.8707x over previous
//
#include <hip/hip_runtime.h>
#include <hip/hip_bf16.h>
#include <math.h>

// Problem constants
#define DM 96
#define DI 192
#define DSTATE 64
#define NH 8
#define HD 24
#define CD 320
#define ZD 520
#define LSEQ 512
#define NSEQ 24            // B(2) * 12 directions
#define NROW (NSEQ*LSEQ)   // 12288

__device__ __forceinline__ float wave_sum64(float v){
  #pragma unroll
  for (int o = 32; o > 0; o >>= 1) v += __shfl_down(v, o);
  return v;
}

__device__ __forceinline__ float silu_f(float x){
  return x / (1.f + expf(-x));
}

// ---------------------------------------------------------------------------
// 1) downsample: pixel-unshuffle(2) -> LN(384) -> @ ds_red_w.T -> res[b,m,vox]
__global__ void k_downsample(const float* __restrict__ x,
                             const float* __restrict__ lnw,
                             const float* __restrict__ lnb,
                             const float* __restrict__ redw,
                             float* __restrict__ res){
  int vox = blockIdx.x;          // b*512 + i*64+j*8+k
  int b = vox >> 9; int r = vox & 511;
  int i = r >> 6, j = (r >> 3) & 7, k = r & 7;
  __shared__ float t[384];
  __shared__ float sm[4];
  int tid = threadIdx.x;
  for (int f = tid; f < 384; f += 128){
    int c = f >> 3; int di = (f >> 2) & 1, dj = (f >> 1) & 1, dk = f & 1;
    int X = 2*i + di, Y = 2*j + dj, Z = 2*k + dk;
    t[f] = x[(((b*48 + c)*16 + X)*16 + Y)*16 + Z];
  }
  __syncthreads();
  float s = 0.f, s2 = 0.f;
  for (int f = tid; f < 384; f += 128){ float v = t[f]; s += v; s2 += v*v; }
  s = wave_sum64(s); s2 = wave_sum64(s2);
  int lane = tid & 63, wv = tid >> 6;
  if (lane == 0){ sm[wv] = s; sm[2+wv] = s2; }
  __syncthreads();
  float mean = (sm[0] + sm[1]) * (1.f/384.f);
  float var  = (sm[2] + sm[3]) * (1.f/384.f) - mean*mean;
  float rstd = rsqrtf(var + 1e-5f);
  __syncthreads();
  for (int f = tid; f < 384; f += 128) t[f] = (t[f]-mean)*rstd*lnw[f] + lnb[f];
  __syncthreads();
  if (tid < 96){
    const float* wrow = redw + tid*384;
    float acc = 0.f;
    #pragma unroll 4
    for (int f = 0; f < 384; f++) acc = fmaf(t[f], wrow[f], acc);
    res[((b*96 + tid)*512) + r] = acc;
  }
}

// ---------------------------------------------------------------------------
// 2) build the 24 sequences: H[s, t, m]
__global__ void k_build_hs(const float* __restrict__ res, float* __restrict__ H){
  int idx = blockIdx.x*blockDim.x + threadIdx.x;
  if (idx >= NSEQ*LSEQ*DM) return;
  int m = idx % DM; int t = (idx/DM) % LSEQ; int s = idx/(DM*LSEQ);
  int b = s / 12, d = s % 12;
  int tt = (d & 2) ? (511 - t) : t;
  int a = tt >> 6, bb = (tt >> 3) & 7, cc = tt & 7;
  int i, j, k;
  int g = d >> 2; bool sw = d & 1;
  if (g == 0){ if (!sw){ i=a; j=bb; k=cc; } else { i=a; k=bb; j=cc; } }
  else if (g == 1){ if (!sw){ j=a; k=bb; i=cc; } else { j=a; i=bb; k=cc; } }
  else { if (!sw){ k=a; i=bb; j=cc; } else { k=a; j=bb; i=cc; } }
  H[idx] = res[((b*96 + m)*512) + (i*64 + j*8 + k)];
}

// ---------------------------------------------------------------------------
// 3) fused (optional add) + LayerNorm over 96
__global__ void k_add_ln(const float* __restrict__ A, const float* __restrict__ Bp,
                         float* __restrict__ Rout, float* __restrict__ U,
                         const float* __restrict__ w, const float* __restrict__ bias){
  int row = blockIdx.x; int tid = threadIdx.x;
  float v = 0.f;
  if (tid < DM){
    v = A[row*DM + tid];
    if (Bp) v += Bp[row*DM + tid];
  }
  float s = wave_sum64(v), s2 = wave_sum64(v*v);
  __shared__ float sm[4];
  int lane = tid & 63, wv = tid >> 6;
  if (lane == 0){ sm[wv] = s; sm[2+wv] = s2; }
  __syncthreads();
  float mean = (sm[0] + sm[1]) * (1.f/96.f);
  float var  = (sm[2] + sm[3]) * (1.f/96.f) - mean*mean;
  float rstd = rsqrtf(var + 1e-5f);
  if (tid < DM){
    if (Rout) Rout[row*DM + tid] = v;
    U[row*DM + tid] = (v-mean)*rstd*w[tid] + bias[tid];
  }
}

// ---------------------------------------------------------------------------
// 4) tiled GEMM: C[m,n] = act(A[m,:K].W[n,:K] + bias[n]) (+C if beta)
//    64x64 tile / block(256), 4x4 micro-tile, KC=32 staged in LDS.
//    K must be a multiple of 32, M a multiple of 64. N arbitrary.
template<int ACT>   // 0 = none, 1 = gelu(exact)
__global__ __launch_bounds__(256)
void k_gemm_t(const float* __restrict__ A, const float* __restrict__ W,
              const float* __restrict__ bias, float* __restrict__ C,
              int N, int K, int beta){
  __shared__ float As[32][68];   // [kk][m], row stride 272B (16B-aligned)
  __shared__ float Ws[32][68];   // [kk][n]
  int m0 = blockIdx.x * 64;
  int n0 = blockIdx.y * 64;
  int tid = threadIdx.x;
  int tn = (tid & 15) * 4;
  int tm = (tid >> 4) * 4;
  float acc[4][4] = {{0.f},{0.f},{0.f},{0.f}};
  for (int k0 = 0; k0 < K; k0 += 32){
    #pragma unroll
    for (int i = 0; i < 8; ++i){
      int idx = tid + i*256;
      int kk = idx & 31, mm = idx >> 5;
      As[kk][mm] = A[(size_t)(m0+mm)*K + k0 + kk];
    }
    #pragma unroll
    for (int i = 0; i < 8; ++i){
      int idx = tid + i*256;
      int kk = idx & 31, nn = idx >> 5;
      int n = n0 + nn;
      Ws[kk][nn] = (n < N) ? W[(size_t)n*K + k0 + kk] : 0.f;
    }
    __syncthreads();
    #pragma unroll
    for (int kk = 0; kk < 32; ++kk){
      float a4[4], w4[4];
      *(float4*)a4 = *(const float4*)&As[kk][tm];
      *(float4*)w4 = *(const float4*)&Ws[kk][tn];
      #pragma unroll
      for (int i = 0; i < 4; i++)
        #pragma unroll
        for (int j = 0; j < 4; j++)
          acc[i][j] = fmaf(a4[i], w4[j], acc[i][j]);
    }
    __syncthreads();
  }
  #pragma unroll
  for (int i = 0; i < 4; i++){
    int m = m0 + tm + i;
    #pragma unroll
    for (int j = 0; j < 4; j++){
      int n = n0 + tn + j;
      if (n < N){
        float v = acc[i][j];
        if (bias) v += bias[n];
        if (ACT == 1) v = 0.5f*v*(1.f + erff(v*0.70710678118654752f));
        if (beta) v += C[(size_t)m*N + n];
        C[(size_t)m*N + n] = v;
      }
    }
  }
}

// ---------------------------------------------------------------------------
// 5) causal conv (4 taps) + bias + silu, float4 over channels
__global__ void k_conv4(const float* __restrict__ ZX, const float* __restrict__ cw,
                        const float* __restrict__ cb, float* __restrict__ XBC){
  int idx = blockIdx.x*blockDim.x + threadIdx.x;
  if (idx >= NSEQ*LSEQ*(CD/4)) return;
  int c4 = idx % (CD/4); int t = (idx/(CD/4)) % LSEQ; int s = idx/((CD/4)*LSEQ);
  int c = c4*4;
  float4 acc = *(const float4*)(cb + c);
  #pragma unroll
  for (int k = 0; k < 4; k++){
    int tt = t - 3 + k;
    if (tt >= 0){
      float4 v = *(const float4*)(ZX + ((size_t)(s*LSEQ + tt))*ZD + DI + c);
      acc.x = fmaf(v.x, cw[(c+0)*4+k], acc.x);
      acc.y = fmaf(v.y, cw[(c+1)*4+k], acc.y);
      acc.z = fmaf(v.z, cw[(c+2)*4+k], acc.z);
      acc.w = fmaf(v.w, cw[(c+3)*4+k], acc.w);
    }
  }
  float4 r;
  r.x = silu_f(acc.x); r.y = silu_f(acc.y);
  r.z = silu_f(acc.z); r.w = silu_f(acc.w);
  *(float4*)(XBC + ((size_t)(s*LSEQ + t))*CD + c) = r;
}

// 6) dt = softplus(raw + bias); dA = exp(-exp(A_log)*dt)
__global__ void k_dt(const float* __restrict__ ZX, const float* __restrict__ dtb,
                     const float* __restrict__ alog, float* __restrict__ DT,
                     float* __restrict__ DA){
  int idx = blockIdx.x*blockDim.x + threadIdx.x;
  if (idx >= NSEQ*LSEQ*NH) return;
  int h = idx % NH; int row = idx / NH;
  float xr = ZX[row*ZD + 512 + h] + dtb[h];
  float dt = (xr > 20.f) ? xr : log1pf(expf(xr));
  DT[idx] = dt;
  DA[idx] = expf(-expf(alog[h]) * dt);
}

// ---------------------------------------------------------------------------
// 7) SSM scan v2: grid = NSEQ*4 (4-way state split), block = 192.
__global__ __launch_bounds__(192)
void k_scan2(const float* __restrict__ XBC, const float* __restrict__ DT,
             const float* __restrict__ DA, float* __restrict__ Y,
             float* __restrict__ YP3){
  int s = blockIdx.x >> 2;
  int nblk = blockIdx.x & 3;
  int tid = threadIdx.x;
  int n_sub = tid & 3;
  int p_grp = tid >> 2;       // 0..47
  int pp = p_grp * 4;
  int h = p_grp / 6;
  int n0 = nblk*16 + n_sub*4;

  __shared__ float sDT[4096];
  __shared__ float sDA[4096];
  {
    const float4* s1 = (const float4*)(DT + (size_t)s*4096);
    const float4* s2 = (const float4*)(DA + (size_t)s*4096);
    float4* d1 = (float4*)sDT; float4* d2 = (float4*)sDA;
    for (int i = tid; i < 1024; i += 192){ d1[i] = s1[i]; d2[i] = s2[i]; }
  }
  __syncthreads();

  const float* xb = XBC + (size_t)s*LSEQ*CD;
  float* dst = (nblk == 0) ? Y : (YP3 + (size_t)(nblk-1)*NROW*DI);
  float* yout = dst + (size_t)s*LSEQ*DI + pp;

  float hr[4][4] = {{0.f}};
  float4 xA = *(const float4*)(xb + pp);
  float4 bA = *(const float4*)(xb + 192 + n0);
  float4 cA = *(const float4*)(xb + 256 + n0);
  float4 xB = *(const float4*)(xb + CD + pp);
  float4 bB = *(const float4*)(xb + CD + 192 + n0);
  float4 cB = *(const float4*)(xb + CD + 256 + n0);

  for (int t = 0; t < LSEQ; ++t){
    int tn = (t + 2 < LSEQ) ? t + 2 : (LSEQ - 1);
    const float* bn = xb + (size_t)tn*CD;
    float4 xN = *(const float4*)(bn + pp);
    float4 bN = *(const float4*)(bn + 192 + n0);
    float4 cN = *(const float4*)(bn + 256 + n0);

    float dAv = sDA[t*8 + h];
    float dtv = sDT[t*8 + h];
    float xq[4] = {xA.x, xA.y, xA.z, xA.w};
    float Bn[4] = {bA.x, bA.y, bA.z, bA.w};
    float Cn[4] = {cA.x, cA.y, cA.z, cA.w};
    float y4[4];
    #pragma unroll
    for (int q = 0; q < 4; ++q){
      float dtx = dtv * xq[q];
      float acc = 0.f;
      #pragma unroll
      for (int n = 0; n < 4; ++n){
        hr[q][n] = fmaf(dAv, hr[q][n], dtx * Bn[n]);
        acc = fmaf(hr[q][n], Cn[n], acc);
      }
      acc += __shfl_xor(acc, 1);
      acc += __shfl_xor(acc, 2);
      y4[q] = acc;
    }
    if (n_sub == 0)
      *(float4*)(yout + (size_t)t*DI) = make_float4(y4[0], y4[1], y4[2], y4[3]);
    xA=xB; bA=bB; cA=cB; xB=xN; bB=bN; cB=cN;
  }
}

// ---------------------------------------------------------------------------
// 8) combine partials + D*xh + silu(z) gate + RMSNorm(192).  In-place on Y.
__global__ __launch_bounds__(192)
void k_gate2(float* __restrict__ Y, const float* __restrict__ YP3,
             const float* __restrict__ XBC, const float* __restrict__ ZX,
             const float* __restrict__ Dv, const float* __restrict__ nw){
  int row = blockIdx.x; int tid = threadIdx.x;
  size_t o = (size_t)row*DI + tid;
  const size_t PS = (size_t)NROW*DI;
  float y = Y[o] + YP3[o] + YP3[PS + o] + YP3[2*PS + o];
  int h = tid / 24;
  float xh = XBC[(size_t)row*CD + tid];
  y += Dv[h] * xh;
  float z = ZX[(size_t)row*ZD + tid];
  y *= silu_f(z);
  float s2 = wave_sum64(y*y);
  __shared__ float sm[3];
  int lane = tid & 63, wv = tid >> 6;
  if (lane == 0) sm[wv] = s2;
  __syncthreads();
  float rms = rsqrtf((sm[0]+sm[1]+sm[2]) * (1.f/192.f) + 1e-5f);
  Y[o] = y * rms * nw[tid];
}

// ---------------------------------------------------------------------------
// 9) merge 12 directions -> output
__global__ void k_merge(const float* __restrict__ F, float* __restrict__ out){
  int idx = blockIdx.x*blockDim.x + threadIdx.x;
  if (idx >= 2*96*512) return;
  int r = idx % 512; int m = (idx/512) % 96; int b = idx/(512*96);
  int i = r >> 6, j = (r >> 3) & 7, k = r & 7;
  int ti = r;
  int tj = j*64 + k*8 + i;
  int tk = k*64 + i*8 + j;
  const float* Fb = F + (size_t)(b*12)*LSEQ*DM;
  float acc = 0.f;
  acc += Fb[(0*LSEQ + ti)*DM + m]        + Fb[(1*LSEQ + ti)*DM + m];
  acc += Fb[(2*LSEQ + (511-ti))*DM + m]  + Fb[(3*LSEQ + (511-ti))*DM + m];
  acc += Fb[(4*LSEQ + tj)*DM + m]        + Fb[(5*LSEQ + tj)*DM + m];
  acc += Fb[(6*LSEQ + (511-tj))*DM + m]  + Fb[(7*LSEQ + (511-tj))*DM + m];
  acc += Fb[(8*LSEQ + tk)*DM + m]        + Fb[(9*LSEQ + tk)*DM + m];
  acc += Fb[(10*LSEQ + (511-tk))*DM + m] + Fb[(11*LSEQ + (511-tk))*DM + m];
  out[idx] = acc * (1.f/12.f);
}

// ---------------------------------------------------------------------------
extern "C" void kernel_launch(void* const* d_in, const int* in_sizes, int n_in,
                              void* d_out, int out_size, void* d_ws, size_t ws_size,
                              hipStream_t stream){
  const float* x        = (const float*)d_in[0];
  const float* ds_ln_w  = (const float*)d_in[1];
  const float* ds_ln_b  = (const float*)d_in[2];
  const float* ds_red_w = (const float*)d_in[3];
  const float* norm1_w  = (const float*)d_in[4];
  const float* norm1_b  = (const float*)d_in[5];
  const float* in_proj_w= (const float*)d_in[6];
  const float* conv_w   = (const float*)d_in[7];
  const float* conv_b   = (const float*)d_in[8];
  const float* dt_bias  = (const float*)d_in[9];
  const float* A_log    = (const float*)d_in[10];
  const float* Dv       = (const float*)d_in[11];
  const float* ssm_nw   = (const float*)d_in[12];
  const float* out_pw   = (const float*)d_in[13];
  const float* norm2_w  = (const float*)d_in[14];
  const float* norm2_b  = (const float*)d_in[15];
  const float* fc1_w    = (const float*)d_in[16];
  const float* fc1_b    = (const float*)d_in[17];
  const float* fc2_w    = (const float*)d_in[18];
  const float* fc2_b    = (const float*)d_in[19];
  const float* normf_w  = (const float*)d_in[20];
  const float* normf_b  = (const float*)d_in[21];
  float* out = (float*)d_out;

  float* ws = (float*)d_ws;
  const size_t NRES = 2*96*512;
  const size_t NHS  = (size_t)NROW*DM;
  const size_t NZX  = (size_t)NROW*ZD;
  const size_t NXBC = (size_t)NROW*CD;
  const size_t NDT  = (size_t)NROW*NH;
  const size_t NY   = (size_t)NROW*DI;
  float* res = ws;
  float* H   = res + NRES;
  float* R   = H + NHS;
  float* U   = R + NHS;
  float* ZX  = U + NHS;
  float* XBC = ZX + NZX;
  float* DT  = XBC + NXBC;
  float* DA  = DT + NDT;
  float* Y   = DA + NDT;
  float* YP3 = Y + NY;
  float* T1  = XBC;             // alias: XBC dead once fc1 runs

  k_downsample<<<2*512, 128, 0, stream>>>(x, ds_ln_w, ds_ln_b, ds_red_w, res);
  k_build_hs<<<(NSEQ*LSEQ*DM + 255)/256, 256, 0, stream>>>(res, H);

  const int MB = NROW/64;   // 192

  for (int l = 0; l < 2; l++){
    const float* n1w = norm1_w + l*DM,  * n1b = norm1_b + l*DM;
    const float* ipw = in_proj_w + (size_t)l*ZD*DM;
    const float* cw  = conv_w + (size_t)l*CD*4, * cb = conv_b + (size_t)l*CD;
    const float* dtb = dt_bias + l*NH, * alog = A_log + l*NH, * dvl = Dv + l*NH;
    const float* snw = ssm_nw + (size_t)l*DI;
    const float* opw = out_pw + (size_t)l*DM*DI;
    const float* n2w = norm2_w + l*DM,  * n2b = norm2_b + l*DM;
    const float* f1w = fc1_w + (size_t)l*DI*DM, * f1b = fc1_b + (size_t)l*DI;
    const float* f2w = fc2_w + (size_t)l*DM*DI, * f2b = fc2_b + (size_t)l*DM;

    k_add_ln<<<NROW, 128, 0, stream>>>(H, l == 0 ? nullptr : R, R, U, n1w, n1b);
    k_gemm_t<0><<<dim3(MB, 9), 256, 0, stream>>>(U, ipw, nullptr, ZX, ZD, DM, 0);
    k_conv4<<<(NSEQ*LSEQ*(CD/4) + 255)/256, 256, 0, stream>>>(ZX, cw, cb, XBC);
    k_dt<<<(NSEQ*LSEQ*NH + 255)/256, 256, 0, stream>>>(ZX, dtb, alog, DT, DA);
    k_scan2<<<NSEQ*4, 192, 0, stream>>>(XBC, DT, DA, Y, YP3);
    k_gate2<<<NROW, 192, 0, stream>>>(Y, YP3, XBC, ZX, dvl, snw);
    k_gemm_t<0><<<dim3(MB, 2), 256, 0, stream>>>(Y, opw, nullptr, R, DM, DI, 1);
    k_add_ln<<<NROW, 128, 0, stream>>>(R, nullptr, nullptr, U, n2w, n2b);
    k_gemm_t<1><<<dim3(MB, 3), 256, 0, stream>>>(U, f1w, f1b, T1, DI, DM, 0);
    k_gemm_t<0><<<dim3(MB, 2), 256, 0, stream>>>(T1, f2w, f2b, H, DM, DI, 0);
  }

  k_add_ln<<<NROW, 128, 0, stream>>>(H, R, nullptr, U, normf_w, normf_b);
  k_merge<<<(2*96*512 + 255)/256, 256, 0, stream>>>(U, out);
}

// Round 4
// 701.753 us; speedup vs baseline: 5.7508x; 1.1494x over previous
//
#include <hip/hip_runtime.h>
#include <hip/hip_bf16.h>
#include <math.h>

// Problem constants
#define DM 96
#define DI 192
#define DSTATE 64
#define NH 8
#define HD 24
#define CD 320
#define ZD 520
#define LSEQ 512
#define NSEQ 24            // B(2) * 12 directions
#define NROW (NSEQ*LSEQ)   // 12288

__device__ __forceinline__ float wave_sum64(float v){
  #pragma unroll
  for (int o = 32; o > 0; o >>= 1) v += __shfl_down(v, o);
  return v;
}

__device__ __forceinline__ float silu_f(float x){
  return x / (1.f + expf(-x));
}

// ---------------------------------------------------------------------------
// 1) downsample: pixel-unshuffle(2) -> LN(384) -> @ ds_red_w.T -> res[b,m,vox]
__global__ void k_downsample(const float* __restrict__ x,
                             const float* __restrict__ lnw,
                             const float* __restrict__ lnb,
                             const float* __restrict__ redw,
                             float* __restrict__ res){
  int vox = blockIdx.x;          // b*512 + i*64+j*8+k
  int b = vox >> 9; int r = vox & 511;
  int i = r >> 6, j = (r >> 3) & 7, k = r & 7;
  __shared__ float t[384];
  __shared__ float sm[4];
  int tid = threadIdx.x;
  for (int f = tid; f < 384; f += 128){
    int c = f >> 3; int di = (f >> 2) & 1, dj = (f >> 1) & 1, dk = f & 1;
    int X = 2*i + di, Y = 2*j + dj, Z = 2*k + dk;
    t[f] = x[(((b*48 + c)*16 + X)*16 + Y)*16 + Z];
  }
  __syncthreads();
  float s = 0.f, s2 = 0.f;
  for (int f = tid; f < 384; f += 128){ float v = t[f]; s += v; s2 += v*v; }
  s = wave_sum64(s); s2 = wave_sum64(s2);
  int lane = tid & 63, wv = tid >> 6;
  if (lane == 0){ sm[wv] = s; sm[2+wv] = s2; }
  __syncthreads();
  float mean = (sm[0] + sm[1]) * (1.f/384.f);
  float var  = (sm[2] + sm[3]) * (1.f/384.f) - mean*mean;
  float rstd = rsqrtf(var + 1e-5f);
  __syncthreads();
  for (int f = tid; f < 384; f += 128) t[f] = (t[f]-mean)*rstd*lnw[f] + lnb[f];
  __syncthreads();
  if (tid < 96){
    const float* wrow = redw + tid*384;
    float acc = 0.f;
    #pragma unroll 4
    for (int f = 0; f < 384; f++) acc = fmaf(t[f], wrow[f], acc);
    res[((b*96 + tid)*512) + r] = acc;
  }
}

// ---------------------------------------------------------------------------
// 2) build the 24 sequences: H[s, t, m]
__global__ void k_build_hs(const float* __restrict__ res, float* __restrict__ H){
  int idx = blockIdx.x*blockDim.x + threadIdx.x;
  if (idx >= NSEQ*LSEQ*DM) return;
  int m = idx % DM; int t = (idx/DM) % LSEQ; int s = idx/(DM*LSEQ);
  int b = s / 12, d = s % 12;
  int tt = (d & 2) ? (511 - t) : t;
  int a = tt >> 6, bb = (tt >> 3) & 7, cc = tt & 7;
  int i, j, k;
  int g = d >> 2; bool sw = d & 1;
  if (g == 0){ if (!sw){ i=a; j=bb; k=cc; } else { i=a; k=bb; j=cc; } }
  else if (g == 1){ if (!sw){ j=a; k=bb; i=cc; } else { j=a; i=bb; k=cc; } }
  else { if (!sw){ k=a; i=bb; j=cc; } else { k=a; j=bb; i=cc; } }
  H[idx] = res[((b*96 + m)*512) + (i*64 + j*8 + k)];
}

// ---------------------------------------------------------------------------
// 3) fused (optional add) + LayerNorm over 96
__global__ void k_add_ln(const float* __restrict__ A, const float* __restrict__ Bp,
                         float* __restrict__ Rout, float* __restrict__ U,
                         const float* __restrict__ w, const float* __restrict__ bias){
  int row = blockIdx.x; int tid = threadIdx.x;
  float v = 0.f;
  if (tid < DM){
    v = A[row*DM + tid];
    if (Bp) v += Bp[row*DM + tid];
  }
  float s = wave_sum64(v), s2 = wave_sum64(v*v);
  __shared__ float sm[4];
  int lane = tid & 63, wv = tid >> 6;
  if (lane == 0){ sm[wv] = s; sm[2+wv] = s2; }
  __syncthreads();
  float mean = (sm[0] + sm[1]) * (1.f/96.f);
  float var  = (sm[2] + sm[3]) * (1.f/96.f) - mean*mean;
  float rstd = rsqrtf(var + 1e-5f);
  if (tid < DM){
    if (Rout) Rout[row*DM + tid] = v;
    U[row*DM + tid] = (v-mean)*rstd*w[tid] + bias[tid];
  }
}

// ---------------------------------------------------------------------------
// 4) tiled GEMM: C[m,n] = act(A[m,:K].W[n,:K] + bias[n]) (+C if beta)
template<int ACT>   // 0 = none, 1 = gelu(exact)
__global__ __launch_bounds__(256)
void k_gemm_t(const float* __restrict__ A, const float* __restrict__ W,
              const float* __restrict__ bias, float* __restrict__ C,
              int N, int K, int beta){
  __shared__ float As[32][68];   // [kk][m]
  __shared__ float Ws[32][68];   // [kk][n]
  int m0 = blockIdx.x * 64;
  int n0 = blockIdx.y * 64;
  int tid = threadIdx.x;
  int tn = (tid & 15) * 4;
  int tm = (tid >> 4) * 4;
  float acc[4][4] = {{0.f},{0.f},{0.f},{0.f}};
  for (int k0 = 0; k0 < K; k0 += 32){
    #pragma unroll
    for (int i = 0; i < 8; ++i){
      int idx = tid + i*256;
      int kk = idx & 31, mm = idx >> 5;
      As[kk][mm] = A[(size_t)(m0+mm)*K + k0 + kk];
    }
    #pragma unroll
    for (int i = 0; i < 8; ++i){
      int idx = tid + i*256;
      int kk = idx & 31, nn = idx >> 5;
      int n = n0 + nn;
      Ws[kk][nn] = (n < N) ? W[(size_t)n*K + k0 + kk] : 0.f;
    }
    __syncthreads();
    #pragma unroll
    for (int kk = 0; kk < 32; ++kk){
      float a4[4], w4[4];
      *(float4*)a4 = *(const float4*)&As[kk][tm];
      *(float4*)w4 = *(const float4*)&Ws[kk][tn];
      #pragma unroll
      for (int i = 0; i < 4; i++)
        #pragma unroll
        for (int j = 0; j < 4; j++)
          acc[i][j] = fmaf(a4[i], w4[j], acc[i][j]);
    }
    __syncthreads();
  }
  #pragma unroll
  for (int i = 0; i < 4; i++){
    int m = m0 + tm + i;
    #pragma unroll
    for (int j = 0; j < 4; j++){
      int n = n0 + tn + j;
      if (n < N){
        float v = acc[i][j];
        if (bias) v += bias[n];
        if (ACT == 1) v = 0.5f*v*(1.f + erff(v*0.70710678118654752f));
        if (beta) v += C[(size_t)m*N + n];
        C[(size_t)m*N + n] = v;
      }
    }
  }
}

// ---------------------------------------------------------------------------
// 5) causal conv (4 taps) + bias + silu, float4 over channels
__global__ void k_conv4(const float* __restrict__ ZX, const float* __restrict__ cw,
                        const float* __restrict__ cb, float* __restrict__ XBC){
  int idx = blockIdx.x*blockDim.x + threadIdx.x;
  if (idx >= NSEQ*LSEQ*(CD/4)) return;
  int c4 = idx % (CD/4); int t = (idx/(CD/4)) % LSEQ; int s = idx/((CD/4)*LSEQ);
  int c = c4*4;
  float4 acc = *(const float4*)(cb + c);
  #pragma unroll
  for (int k = 0; k < 4; k++){
    int tt = t - 3 + k;
    if (tt >= 0){
      float4 v = *(const float4*)(ZX + ((size_t)(s*LSEQ + tt))*ZD + DI + c);
      acc.x = fmaf(v.x, cw[(c+0)*4+k], acc.x);
      acc.y = fmaf(v.y, cw[(c+1)*4+k], acc.y);
      acc.z = fmaf(v.z, cw[(c+2)*4+k], acc.z);
      acc.w = fmaf(v.w, cw[(c+3)*4+k], acc.w);
    }
  }
  float4 r;
  r.x = silu_f(acc.x); r.y = silu_f(acc.y);
  r.z = silu_f(acc.z); r.w = silu_f(acc.w);
  *(float4*)(XBC + ((size_t)(s*LSEQ + t))*CD + c) = r;
}

// 6) dt = softplus(raw + bias); dA = exp(-exp(A_log)*dt)
__global__ void k_dt(const float* __restrict__ ZX, const float* __restrict__ dtb,
                     const float* __restrict__ alog, float* __restrict__ DT,
                     float* __restrict__ DA){
  int idx = blockIdx.x*blockDim.x + threadIdx.x;
  if (idx >= NSEQ*LSEQ*NH) return;
  int h = idx % NH; int row = idx / NH;
  float xr = ZX[row*ZD + 512 + h] + dtb[h];
  float dt = (xr > 20.f) ? xr : log1pf(expf(xr));
  DT[idx] = dt;
  DA[idx] = expf(-expf(alog[h]) * dt);
}

// ---------------------------------------------------------------------------
// 7) SSM scan v3: shfl-free. grid = NSEQ*4 (4-way state split), block = 192.
//    thread = one head-dim p (0..191), owns hr[16] = its n-block's 16 cols.
//    B/C slices staged per 64-step chunk in double-buffered LDS (broadcast).
#define TCH 64
__global__ __launch_bounds__(192)
void k_scan3(const float* __restrict__ XBC, const float* __restrict__ DT,
             const float* __restrict__ DA, float* __restrict__ Y,
             float* __restrict__ YP3){
  int s = blockIdx.x >> 2;
  int nblk = blockIdx.x & 3;
  int tid = threadIdx.x;       // p = tid
  int h = tid / HD;
  int n0 = nblk*16;

  __shared__ float sDT[4096];
  __shared__ float sDA[4096];
  __shared__ float sB[2][TCH][16];
  __shared__ float sC[2][TCH][16];
  {
    const float4* s1 = (const float4*)(DT + (size_t)s*4096);
    const float4* s2 = (const float4*)(DA + (size_t)s*4096);
    float4* d1 = (float4*)sDT; float4* d2 = (float4*)sDA;
    for (int i = tid; i < 1024; i += 192){ d1[i] = s1[i]; d2[i] = s2[i]; }
  }
  const float* xb = XBC + (size_t)s*LSEQ*CD;

  // stage chunk [tbase, tbase+TCH) of B/C into buffer buf
  auto stage = [&](int buf, int tbase){
    #pragma unroll
    for (int i = tid; i < TCH*4; i += 192){
      int row = i >> 2, q = (i & 3) * 4;
      const float* src = xb + (size_t)(tbase + row)*CD + 192;
      *(float4*)&sB[buf][row][q] = *(const float4*)(src + n0 + q);
      *(float4*)&sC[buf][row][q] = *(const float4*)(src + 64 + n0 + q);
    }
  };

  stage(0, 0);

  float* dst = (nblk == 0) ? Y : (YP3 + (size_t)(nblk-1)*NROW*DI);
  float* yout = dst + (size_t)s*LSEQ*DI + tid;

  float hr[16];
  #pragma unroll
  for (int n = 0; n < 16; n++) hr[n] = 0.f;

  float xv = xb[tid];              // x for t=0 (thread's own p), coalesced
  __syncthreads();

  for (int tc = 0; tc < LSEQ; tc += TCH){
    int buf = (tc/TCH) & 1;
    if (tc + TCH < LSEQ) stage(buf^1, tc + TCH);
    #pragma unroll 4
    for (int t = 0; t < TCH; ++t){
      int tg = tc + t;
      // prefetch next x
      float xnext = (tg + 1 < LSEQ) ? xb[(size_t)(tg+1)*CD + tid] : 0.f;
      float dAv = sDA[tg*8 + h];
      float dtv = sDT[tg*8 + h];
      float b[16], c[16];
      *(float4*)&b[0]  = *(const float4*)&sB[buf][t][0];
      *(float4*)&b[4]  = *(const float4*)&sB[buf][t][4];
      *(float4*)&b[8]  = *(const float4*)&sB[buf][t][8];
      *(float4*)&b[12] = *(const float4*)&sB[buf][t][12];
      *(float4*)&c[0]  = *(const float4*)&sC[buf][t][0];
      *(float4*)&c[4]  = *(const float4*)&sC[buf][t][4];
      *(float4*)&c[8]  = *(const float4*)&sC[buf][t][8];
      *(float4*)&c[12] = *(const float4*)&sC[buf][t][12];
      float dtx = dtv * xv;
      float a0 = 0.f, a1 = 0.f, a2 = 0.f, a3 = 0.f;
      #pragma unroll
      for (int n = 0; n < 4; n++){
        hr[n]    = fmaf(dAv, hr[n],    dtx * b[n]);    a0 = fmaf(hr[n],    c[n],    a0);
        hr[4+n]  = fmaf(dAv, hr[4+n],  dtx * b[4+n]);  a1 = fmaf(hr[4+n],  c[4+n],  a1);
        hr[8+n]  = fmaf(dAv, hr[8+n],  dtx * b[8+n]);  a2 = fmaf(hr[8+n],  c[8+n],  a2);
        hr[12+n] = fmaf(dAv, hr[12+n], dtx * b[12+n]); a3 = fmaf(hr[12+n], c[12+n], a3);
      }
      yout[(size_t)tg*DI] = (a0 + a1) + (a2 + a3);
      xv = xnext;
    }
    __syncthreads();
  }
}

// ---------------------------------------------------------------------------
// 8) combine partials + D*xh + silu(z) gate + RMSNorm(192).  In-place on Y.
__global__ __launch_bounds__(192)
void k_gate2(float* __restrict__ Y, const float* __restrict__ YP3,
             const float* __restrict__ XBC, const float* __restrict__ ZX,
             const float* __restrict__ Dv, const float* __restrict__ nw){
  int row = blockIdx.x; int tid = threadIdx.x;
  size_t o = (size_t)row*DI + tid;
  const size_t PS = (size_t)NROW*DI;
  float y = Y[o] + YP3[o] + YP3[PS + o] + YP3[2*PS + o];
  int h = tid / 24;
  float xh = XBC[(size_t)row*CD + tid];
  y += Dv[h] * xh;
  float z = ZX[(size_t)row*ZD + tid];
  y *= silu_f(z);
  float s2 = wave_sum64(y*y);
  __shared__ float sm[3];
  int lane = tid & 63, wv = tid >> 6;
  if (lane == 0) sm[wv] = s2;
  __syncthreads();
  float rms = rsqrtf((sm[0]+sm[1]+sm[2]) * (1.f/192.f) + 1e-5f);
  Y[o] = y * rms * nw[tid];
}

// ---------------------------------------------------------------------------
// 9) merge 12 directions -> output
__global__ void k_merge(const float* __restrict__ F, float* __restrict__ out){
  int idx = blockIdx.x*blockDim.x + threadIdx.x;
  if (idx >= 2*96*512) return;
  int r = idx % 512; int m = (idx/512) % 96; int b = idx/(512*96);
  int i = r >> 6, j = (r >> 3) & 7, k = r & 7;
  int ti = r;
  int tj = j*64 + k*8 + i;
  int tk = k*64 + i*8 + j;
  const float* Fb = F + (size_t)(b*12)*LSEQ*DM;
  float acc = 0.f;
  acc += Fb[(0*LSEQ + ti)*DM + m]        + Fb[(1*LSEQ + ti)*DM + m];
  acc += Fb[(2*LSEQ + (511-ti))*DM + m]  + Fb[(3*LSEQ + (511-ti))*DM + m];
  acc += Fb[(4*LSEQ + tj)*DM + m]        + Fb[(5*LSEQ + tj)*DM + m];
  acc += Fb[(6*LSEQ + (511-tj))*DM + m]  + Fb[(7*LSEQ + (511-tj))*DM + m];
  acc += Fb[(8*LSEQ + tk)*DM + m]        + Fb[(9*LSEQ + tk)*DM + m];
  acc += Fb[(10*LSEQ + (511-tk))*DM + m] + Fb[(11*LSEQ + (511-tk))*DM + m];
  out[idx] = acc * (1.f/12.f);
}

// ---------------------------------------------------------------------------
extern "C" void kernel_launch(void* const* d_in, const int* in_sizes, int n_in,
                              void* d_out, int out_size, void* d_ws, size_t ws_size,
                              hipStream_t stream){
  const float* x        = (const float*)d_in[0];
  const float* ds_ln_w  = (const float*)d_in[1];
  const float* ds_ln_b  = (const float*)d_in[2];
  const float* ds_red_w = (const float*)d_in[3];
  const float* norm1_w  = (const float*)d_in[4];
  const float* norm1_b  = (const float*)d_in[5];
  const float* in_proj_w= (const float*)d_in[6];
  const float* conv_w   = (const float*)d_in[7];
  const float* conv_b   = (const float*)d_in[8];
  const float* dt_bias  = (const float*)d_in[9];
  const float* A_log    = (const float*)d_in[10];
  const float* Dv       = (const float*)d_in[11];
  const float* ssm_nw   = (const float*)d_in[12];
  const float* out_pw   = (const float*)d_in[13];
  const float* norm2_w  = (const float*)d_in[14];
  const float* norm2_b  = (const float*)d_in[15];
  const float* fc1_w    = (const float*)d_in[16];
  const float* fc1_b    = (const float*)d_in[17];
  const float* fc2_w    = (const float*)d_in[18];
  const float* fc2_b    = (const float*)d_in[19];
  const float* normf_w  = (const float*)d_in[20];
  const float* normf_b  = (const float*)d_in[21];
  float* out = (float*)d_out;

  float* ws = (float*)d_ws;
  const size_t NRES = 2*96*512;
  const size_t NHS  = (size_t)NROW*DM;
  const size_t NZX  = (size_t)NROW*ZD;
  const size_t NXBC = (size_t)NROW*CD;
  const size_t NDT  = (size_t)NROW*NH;
  const size_t NY   = (size_t)NROW*DI;
  float* res = ws;
  float* H   = res + NRES;
  float* R   = H + NHS;
  float* U   = R + NHS;
  float* ZX  = U + NHS;
  float* XBC = ZX + NZX;
  float* DT  = XBC + NXBC;
  float* DA  = DT + NDT;
  float* Y   = DA + NDT;
  float* YP3 = Y + NY;
  float* T1  = XBC;             // alias: XBC dead once fc1 runs

  k_downsample<<<2*512, 128, 0, stream>>>(x, ds_ln_w, ds_ln_b, ds_red_w, res);
  k_build_hs<<<(NSEQ*LSEQ*DM + 255)/256, 256, 0, stream>>>(res, H);

  const int MB = NROW/64;   // 192

  for (int l = 0; l < 2; l++){
    const float* n1w = norm1_w + l*DM,  * n1b = norm1_b + l*DM;
    const float* ipw = in_proj_w + (size_t)l*ZD*DM;
    const float* cw  = conv_w + (size_t)l*CD*4, * cb = conv_b + (size_t)l*CD;
    const float* dtb = dt_bias + l*NH, * alog = A_log + l*NH, * dvl = Dv + l*NH;
    const float* snw = ssm_nw + (size_t)l*DI;
    const float* opw = out_pw + (size_t)l*DM*DI;
    const float* n2w = norm2_w + l*DM,  * n2b = norm2_b + l*DM;
    const float* f1w = fc1_w + (size_t)l*DI*DM, * f1b = fc1_b + (size_t)l*DI;
    const float* f2w = fc2_w + (size_t)l*DM*DI, * f2b = fc2_b + (size_t)l*DM;

    k_add_ln<<<NROW, 128, 0, stream>>>(H, l == 0 ? nullptr : R, R, U, n1w, n1b);
    k_gemm_t<0><<<dim3(MB, 9), 256, 0, stream>>>(U, ipw, nullptr, ZX, ZD, DM, 0);
    k_conv4<<<(NSEQ*LSEQ*(CD/4) + 255)/256, 256, 0, stream>>>(ZX, cw, cb, XBC);
    k_dt<<<(NSEQ*LSEQ*NH + 255)/256, 256, 0, stream>>>(ZX, dtb, alog, DT, DA);
    k_scan3<<<NSEQ*4, 192, 0, stream>>>(XBC, DT, DA, Y, YP3);
    k_gate2<<<NROW, 192, 0, stream>>>(Y, YP3, XBC, ZX, dvl, snw);
    k_gemm_t<0><<<dim3(MB, 2), 256, 0, stream>>>(Y, opw, nullptr, R, DM, DI, 1);
    k_add_ln<<<NROW, 128, 0, stream>>>(R, nullptr, nullptr, U, n2w, n2b);
    k_gemm_t<1><<<dim3(MB, 3), 256, 0, stream>>>(U, f1w, f1b, T1, DI, DM, 0);
    k_gemm_t<0><<<dim3(MB, 2), 256, 0, stream>>>(T1, f2w, f2b, H, DM, DI, 0);
  }

  k_add_ln<<<NROW, 128, 0, stream>>>(H, R, nullptr, U, normf_w, normf_b);
  k_merge<<<(2*96*512 + 255)/256, 256, 0, stream>>>(U, out);
}

// Round 5
// 597.222 us; speedup vs baseline: 6.7574x; 1.1750x over previous
//
#include <hip/hip_runtime.h>
#include <hip/hip_bf16.h>
#include <math.h>

// Problem constants
#define DM 96
#define DI 192
#define DSTATE 64
#define NH 8
#define HD 24
#define CD 320
#define ZD 520
#define LSEQ 512
#define NSEQ 24            // B(2) * 12 directions
#define NROW (NSEQ*LSEQ)   // 12288
#define LC 64              // scan chunk length
#define NCH (LSEQ/LC)      // 8 chunks

__device__ __forceinline__ float wave_sum64(float v){
  #pragma unroll
  for (int o = 32; o > 0; o >>= 1) v += __shfl_down(v, o);
  return v;
}

__device__ __forceinline__ float silu_f(float x){
  return x / (1.f + expf(-x));
}

// ---------------------------------------------------------------------------
// 1) downsample: pixel-unshuffle(2) -> LN(384) -> @ ds_red_w.T -> res[b,m,vox]
__global__ void k_downsample(const float* __restrict__ x,
                             const float* __restrict__ lnw,
                             const float* __restrict__ lnb,
                             const float* __restrict__ redw,
                             float* __restrict__ res){
  int vox = blockIdx.x;          // b*512 + i*64+j*8+k
  int b = vox >> 9; int r = vox & 511;
  int i = r >> 6, j = (r >> 3) & 7, k = r & 7;
  __shared__ float t[384];
  __shared__ float sm[4];
  int tid = threadIdx.x;
  for (int f = tid; f < 384; f += 128){
    int c = f >> 3; int di = (f >> 2) & 1, dj = (f >> 1) & 1, dk = f & 1;
    int X = 2*i + di, Y = 2*j + dj, Z = 2*k + dk;
    t[f] = x[(((b*48 + c)*16 + X)*16 + Y)*16 + Z];
  }
  __syncthreads();
  float s = 0.f, s2 = 0.f;
  for (int f = tid; f < 384; f += 128){ float v = t[f]; s += v; s2 += v*v; }
  s = wave_sum64(s); s2 = wave_sum64(s2);
  int lane = tid & 63, wv = tid >> 6;
  if (lane == 0){ sm[wv] = s; sm[2+wv] = s2; }
  __syncthreads();
  float mean = (sm[0] + sm[1]) * (1.f/384.f);
  float var  = (sm[2] + sm[3]) * (1.f/384.f) - mean*mean;
  float rstd = rsqrtf(var + 1e-5f);
  __syncthreads();
  for (int f = tid; f < 384; f += 128) t[f] = (t[f]-mean)*rstd*lnw[f] + lnb[f];
  __syncthreads();
  if (tid < 96){
    const float* wrow = redw + tid*384;
    float acc = 0.f;
    #pragma unroll 4
    for (int f = 0; f < 384; f++) acc = fmaf(t[f], wrow[f], acc);
    res[((b*96 + tid)*512) + r] = acc;
  }
}

// ---------------------------------------------------------------------------
// 2) build the 24 sequences: H[s, t, m]
__global__ void k_build_hs(const float* __restrict__ res, float* __restrict__ H){
  int idx = blockIdx.x*blockDim.x + threadIdx.x;
  if (idx >= NSEQ*LSEQ*DM) return;
  int m = idx % DM; int t = (idx/DM) % LSEQ; int s = idx/(DM*LSEQ);
  int b = s / 12, d = s % 12;
  int tt = (d & 2) ? (511 - t) : t;
  int a = tt >> 6, bb = (tt >> 3) & 7, cc = tt & 7;
  int i, j, k;
  int g = d >> 2; bool sw = d & 1;
  if (g == 0){ if (!sw){ i=a; j=bb; k=cc; } else { i=a; k=bb; j=cc; } }
  else if (g == 1){ if (!sw){ j=a; k=bb; i=cc; } else { j=a; i=bb; k=cc; } }
  else { if (!sw){ k=a; i=bb; j=cc; } else { k=a; j=bb; i=cc; } }
  H[idx] = res[((b*96 + m)*512) + (i*64 + j*8 + k)];
}

// ---------------------------------------------------------------------------
// 3) fused (optional add) + LayerNorm over 96
__global__ void k_add_ln(const float* __restrict__ A, const float* __restrict__ Bp,
                         float* __restrict__ Rout, float* __restrict__ U,
                         const float* __restrict__ w, const float* __restrict__ bias){
  int row = blockIdx.x; int tid = threadIdx.x;
  float v = 0.f;
  if (tid < DM){
    v = A[row*DM + tid];
    if (Bp) v += Bp[row*DM + tid];
  }
  float s = wave_sum64(v), s2 = wave_sum64(v*v);
  __shared__ float sm[4];
  int lane = tid & 63, wv = tid >> 6;
  if (lane == 0){ sm[wv] = s; sm[2+wv] = s2; }
  __syncthreads();
  float mean = (sm[0] + sm[1]) * (1.f/96.f);
  float var  = (sm[2] + sm[3]) * (1.f/96.f) - mean*mean;
  float rstd = rsqrtf(var + 1e-5f);
  if (tid < DM){
    if (Rout) Rout[row*DM + tid] = v;
    U[row*DM + tid] = (v-mean)*rstd*w[tid] + bias[tid];
  }
}

// ---------------------------------------------------------------------------
// 4) tiled GEMM: C[m,n] = act(A[m,:K].W[n,:K] + bias[n]) (+C if beta)
template<int ACT>   // 0 = none, 1 = gelu(exact)
__global__ __launch_bounds__(256)
void k_gemm_t(const float* __restrict__ A, const float* __restrict__ W,
              const float* __restrict__ bias, float* __restrict__ C,
              int N, int K, int beta){
  __shared__ float As[32][68];   // [kk][m]
  __shared__ float Ws[32][68];   // [kk][n]
  int m0 = blockIdx.x * 64;
  int n0 = blockIdx.y * 64;
  int tid = threadIdx.x;
  int tn = (tid & 15) * 4;
  int tm = (tid >> 4) * 4;
  float acc[4][4] = {{0.f},{0.f},{0.f},{0.f}};
  for (int k0 = 0; k0 < K; k0 += 32){
    #pragma unroll
    for (int i = 0; i < 8; ++i){
      int idx = tid + i*256;
      int kk = idx & 31, mm = idx >> 5;
      As[kk][mm] = A[(size_t)(m0+mm)*K + k0 + kk];
    }
    #pragma unroll
    for (int i = 0; i < 8; ++i){
      int idx = tid + i*256;
      int kk = idx & 31, nn = idx >> 5;
      int n = n0 + nn;
      Ws[kk][nn] = (n < N) ? W[(size_t)n*K + k0 + kk] : 0.f;
    }
    __syncthreads();
    #pragma unroll
    for (int kk = 0; kk < 32; ++kk){
      float a4[4], w4[4];
      *(float4*)a4 = *(const float4*)&As[kk][tm];
      *(float4*)w4 = *(const float4*)&Ws[kk][tn];
      #pragma unroll
      for (int i = 0; i < 4; i++)
        #pragma unroll
        for (int j = 0; j < 4; j++)
          acc[i][j] = fmaf(a4[i], w4[j], acc[i][j]);
    }
    __syncthreads();
  }
  #pragma unroll
  for (int i = 0; i < 4; i++){
    int m = m0 + tm + i;
    #pragma unroll
    for (int j = 0; j < 4; j++){
      int n = n0 + tn + j;
      if (n < N){
        float v = acc[i][j];
        if (bias) v += bias[n];
        if (ACT == 1) v = 0.5f*v*(1.f + erff(v*0.70710678118654752f));
        if (beta) v += C[(size_t)m*N + n];
        C[(size_t)m*N + n] = v;
      }
    }
  }
}

// ---------------------------------------------------------------------------
// 5) causal conv (4 taps) + bias + silu, float4 over channels
__global__ void k_conv4(const float* __restrict__ ZX, const float* __restrict__ cw,
                        const float* __restrict__ cb, float* __restrict__ XBC){
  int idx = blockIdx.x*blockDim.x + threadIdx.x;
  if (idx >= NSEQ*LSEQ*(CD/4)) return;
  int c4 = idx % (CD/4); int t = (idx/(CD/4)) % LSEQ; int s = idx/((CD/4)*LSEQ);
  int c = c4*4;
  float4 acc = *(const float4*)(cb + c);
  #pragma unroll
  for (int k = 0; k < 4; k++){
    int tt = t - 3 + k;
    if (tt >= 0){
      float4 v = *(const float4*)(ZX + ((size_t)(s*LSEQ + tt))*ZD + DI + c);
      acc.x = fmaf(v.x, cw[(c+0)*4+k], acc.x);
      acc.y = fmaf(v.y, cw[(c+1)*4+k], acc.y);
      acc.z = fmaf(v.z, cw[(c+2)*4+k], acc.z);
      acc.w = fmaf(v.w, cw[(c+3)*4+k], acc.w);
    }
  }
  float4 r;
  r.x = silu_f(acc.x); r.y = silu_f(acc.y);
  r.z = silu_f(acc.z); r.w = silu_f(acc.w);
  *(float4*)(XBC + ((size_t)(s*LSEQ + t))*CD + c) = r;
}

// 6) dt = softplus(raw + bias); dA = exp(-exp(A_log)*dt)
__global__ void k_dt(const float* __restrict__ ZX, const float* __restrict__ dtb,
                     const float* __restrict__ alog, float* __restrict__ DT,
                     float* __restrict__ DA){
  int idx = blockIdx.x*blockDim.x + threadIdx.x;
  if (idx >= NSEQ*LSEQ*NH) return;
  int h = idx % NH; int row = idx / NH;
  float xr = ZX[row*ZD + 512 + h] + dtb[h];
  float dt = (xr > 20.f) ? xr : log1pf(expf(xr));
  DT[idx] = dt;
  DA[idx] = expf(-expf(alog[h]) * dt);
}

// ---------------------------------------------------------------------------
// 7a) chunked scan pass A: local scan per (s, nblk, chunk) with h_in = 0.
//     grid = NSEQ*4*NCH = 768, block = 192 (thread = head-dim p).
//     Writes local y into partial buffers, final local state S, chunk product P.
__global__ __launch_bounds__(192)
void k_scanA(const float* __restrict__ XBC, const float* __restrict__ DT,
             const float* __restrict__ DA, float* __restrict__ Y,
             float* __restrict__ YP3, float* __restrict__ Sbuf,
             float* __restrict__ Pbuf){
  int bid = blockIdx.x;
  int c = bid & (NCH-1);
  int nblk = (bid >> 3) & 3;
  int s = bid >> 5;
  int tid = threadIdx.x;       // p
  int h = tid / HD;
  int n0 = nblk*16;
  int t0 = c*LC;

  __shared__ float sDT[LC*8];
  __shared__ float sDA[LC*8];
  __shared__ float sB[LC][16];
  __shared__ float sC[LC][16];
  {
    const float4* s1 = (const float4*)(DT + ((size_t)s*LSEQ + t0)*8);
    const float4* s2 = (const float4*)(DA + ((size_t)s*LSEQ + t0)*8);
    float4* d1 = (float4*)sDT; float4* d2 = (float4*)sDA;
    for (int i = tid; i < LC*2; i += 192){ d1[i] = s1[i]; d2[i] = s2[i]; }
  }
  const float* xb = XBC + (size_t)s*LSEQ*CD;
  for (int i = tid; i < LC*4; i += 192){
    int row = i >> 2, q = (i & 3) * 4;
    const float* src = xb + (size_t)(t0 + row)*CD + 192;
    *(float4*)&sB[row][q] = *(const float4*)(src + n0 + q);
    *(float4*)&sC[row][q] = *(const float4*)(src + 64 + n0 + q);
  }
  __syncthreads();

  float* dst = (nblk == 0) ? Y : (YP3 + (size_t)(nblk-1)*NROW*DI);
  float* yout = dst + ((size_t)s*LSEQ + t0)*DI + tid;

  float hr[16];
  #pragma unroll
  for (int n = 0; n < 16; n++) hr[n] = 0.f;

  // x register pipeline, depth 4
  float xq[4], xn[4];
  #pragma unroll
  for (int i = 0; i < 4; i++) xq[i] = xb[(size_t)(t0+i)*CD + tid];

  for (int tc = 0; tc < LC; tc += 4){
    if (tc + 4 < LC){
      #pragma unroll
      for (int i = 0; i < 4; i++) xn[i] = xb[(size_t)(t0+tc+4+i)*CD + tid];
    }
    #pragma unroll
    for (int t4 = 0; t4 < 4; ++t4){
      int t = tc + t4;
      float dAv = sDA[t*8 + h];
      float dtv = sDT[t*8 + h];
      float b[16], cv[16];
      *(float4*)&b[0]  = *(const float4*)&sB[t][0];
      *(float4*)&b[4]  = *(const float4*)&sB[t][4];
      *(float4*)&b[8]  = *(const float4*)&sB[t][8];
      *(float4*)&b[12] = *(const float4*)&sB[t][12];
      *(float4*)&cv[0]  = *(const float4*)&sC[t][0];
      *(float4*)&cv[4]  = *(const float4*)&sC[t][4];
      *(float4*)&cv[8]  = *(const float4*)&sC[t][8];
      *(float4*)&cv[12] = *(const float4*)&sC[t][12];
      float dtx = dtv * xq[t4];
      float a0 = 0.f, a1 = 0.f, a2 = 0.f, a3 = 0.f;
      #pragma unroll
      for (int n = 0; n < 4; n++){
        hr[n]    = fmaf(dAv, hr[n],    dtx * b[n]);    a0 = fmaf(hr[n],    cv[n],    a0);
        hr[4+n]  = fmaf(dAv, hr[4+n],  dtx * b[4+n]);  a1 = fmaf(hr[4+n],  cv[4+n],  a1);
        hr[8+n]  = fmaf(dAv, hr[8+n],  dtx * b[8+n]);  a2 = fmaf(hr[8+n],  cv[8+n],  a2);
        hr[12+n] = fmaf(dAv, hr[12+n], dtx * b[12+n]); a3 = fmaf(hr[12+n], cv[12+n], a3);
      }
      yout[(size_t)t*DI] = (a0 + a1) + (a2 + a3);
    }
    #pragma unroll
    for (int i = 0; i < 4; i++) xq[i] = xn[i];
  }

  // chunk-final local state
  float* Sp = Sbuf + ((size_t)bid*192 + tid)*16;
  #pragma unroll
  for (int n = 0; n < 16; n += 4)
    *(float4*)(Sp + n) = make_float4(hr[n], hr[n+1], hr[n+2], hr[n+3]);
  // per-head full-chunk dA product
  if (tid < 8){
    float p = 1.f;
    for (int t = 0; t < LC; t++) p *= sDA[t*8 + tid];
    Pbuf[((size_t)s*NCH + c)*8 + tid] = p;
  }
}

// ---------------------------------------------------------------------------
// 7b) chunked scan pass C: y_t += cp_t * (C_t . H_in).  Same grid as pass A.
__global__ __launch_bounds__(192)
void k_scanC(const float* __restrict__ XBC, const float* __restrict__ DA,
             const float* __restrict__ Sbuf, const float* __restrict__ Pbuf,
             float* __restrict__ Y, float* __restrict__ YP3){
  int bid = blockIdx.x;
  int c = bid & (NCH-1);
  if (c == 0) return;                 // first chunk needs no correction
  int nblk = (bid >> 3) & 3;
  int s = bid >> 5;
  int tid = threadIdx.x;
  int h = tid / HD;
  int n0 = nblk*16;
  int t0 = c*LC;

  __shared__ float sC[LC][16];
  __shared__ float scp[LC*8];   // staged DA chunk, then in-place cumprod
  __shared__ float sP[NCH*8];

  const float* xb = XBC + (size_t)s*LSEQ*CD;
  for (int i = tid; i < LC*4; i += 192){
    int row = i >> 2, q = (i & 3) * 4;
    *(float4*)&sC[row][q] =
      *(const float4*)(xb + (size_t)(t0 + row)*CD + 192 + 64 + n0 + q);
  }
  {
    const float* asrc = DA + ((size_t)s*LSEQ + t0)*8;
    for (int i = tid; i < LC*8; i += 192) scp[i] = asrc[i];
  }
  if (tid < NCH*8) sP[tid] = Pbuf[(size_t)s*NCH*8 + tid];
  __syncthreads();

  if (tid < 8){
    float p = 1.f;
    for (int t = 0; t < LC; t++){ p *= scp[t*8 + tid]; scp[t*8 + tid] = p; }
  }
  // H_in recursion over earlier chunks (registers; runs on all threads)
  float H[16];
  #pragma unroll
  for (int n = 0; n < 16; n++) H[n] = 0.f;
  for (int cc = 0; cc < c; ++cc){
    const float* Sp = Sbuf + ((((size_t)(s*4 + nblk)*NCH) + cc)*192 + tid)*16;
    float Pv = sP[cc*8 + h];
    float sv[16];
    #pragma unroll
    for (int n = 0; n < 16; n += 4) *(float4*)&sv[n] = *(const float4*)(Sp + n);
    #pragma unroll
    for (int n = 0; n < 16; n++) H[n] = fmaf(Pv, H[n], sv[n]);
  }
  __syncthreads();

  float* dst = (nblk == 0) ? Y : (YP3 + (size_t)(nblk-1)*NROW*DI);
  float* yout = dst + ((size_t)s*LSEQ + t0)*DI + tid;

  for (int t = 0; t < LC; t += 4){
    float yold[4];
    #pragma unroll
    for (int i = 0; i < 4; i++) yold[i] = yout[(size_t)(t+i)*DI];
    #pragma unroll
    for (int i = 0; i < 4; i++){
      float dot = 0.f;
      #pragma unroll
      for (int n = 0; n < 16; n++) dot = fmaf(sC[t+i][n], H[n], dot);
      yout[(size_t)(t+i)*DI] = yold[i] + scp[(t+i)*8 + h]*dot;
    }
  }
}

// ---------------------------------------------------------------------------
// 8) combine partials + D*xh + silu(z) gate + RMSNorm(192).  In-place on Y.
__global__ __launch_bounds__(192)
void k_gate2(float* __restrict__ Y, const float* __restrict__ YP3,
             const float* __restrict__ XBC, const float* __restrict__ ZX,
             const float* __restrict__ Dv, const float* __restrict__ nw){
  int row = blockIdx.x; int tid = threadIdx.x;
  size_t o = (size_t)row*DI + tid;
  const size_t PS = (size_t)NROW*DI;
  float y = Y[o] + YP3[o] + YP3[PS + o] + YP3[2*PS + o];
  int h = tid / 24;
  float xh = XBC[(size_t)row*CD + tid];
  y += Dv[h] * xh;
  float z = ZX[(size_t)row*ZD + tid];
  y *= silu_f(z);
  float s2 = wave_sum64(y*y);
  __shared__ float sm[3];
  int lane = tid & 63, wv = tid >> 6;
  if (lane == 0) sm[wv] = s2;
  __syncthreads();
  float rms = rsqrtf((sm[0]+sm[1]+sm[2]) * (1.f/192.f) + 1e-5f);
  Y[o] = y * rms * nw[tid];
}

// ---------------------------------------------------------------------------
// 9) merge 12 directions -> output
__global__ void k_merge(const float* __restrict__ F, float* __restrict__ out){
  int idx = blockIdx.x*blockDim.x + threadIdx.x;
  if (idx >= 2*96*512) return;
  int r = idx % 512; int m = (idx/512) % 96; int b = idx/(512*96);
  int i = r >> 6, j = (r >> 3) & 7, k = r & 7;
  int ti = r;
  int tj = j*64 + k*8 + i;
  int tk = k*64 + i*8 + j;
  const float* Fb = F + (size_t)(b*12)*LSEQ*DM;
  float acc = 0.f;
  acc += Fb[(0*LSEQ + ti)*DM + m]        + Fb[(1*LSEQ + ti)*DM + m];
  acc += Fb[(2*LSEQ + (511-ti))*DM + m]  + Fb[(3*LSEQ + (511-ti))*DM + m];
  acc += Fb[(4*LSEQ + tj)*DM + m]        + Fb[(5*LSEQ + tj)*DM + m];
  acc += Fb[(6*LSEQ + (511-tj))*DM + m]  + Fb[(7*LSEQ + (511-tj))*DM + m];
  acc += Fb[(8*LSEQ + tk)*DM + m]        + Fb[(9*LSEQ + tk)*DM + m];
  acc += Fb[(10*LSEQ + (511-tk))*DM + m] + Fb[(11*LSEQ + (511-tk))*DM + m];
  out[idx] = acc * (1.f/12.f);
}

// ---------------------------------------------------------------------------
extern "C" void kernel_launch(void* const* d_in, const int* in_sizes, int n_in,
                              void* d_out, int out_size, void* d_ws, size_t ws_size,
                              hipStream_t stream){
  const float* x        = (const float*)d_in[0];
  const float* ds_ln_w  = (const float*)d_in[1];
  const float* ds_ln_b  = (const float*)d_in[2];
  const float* ds_red_w = (const float*)d_in[3];
  const float* norm1_w  = (const float*)d_in[4];
  const float* norm1_b  = (const float*)d_in[5];
  const float* in_proj_w= (const float*)d_in[6];
  const float* conv_w   = (const float*)d_in[7];
  const float* conv_b   = (const float*)d_in[8];
  const float* dt_bias  = (const float*)d_in[9];
  const float* A_log    = (const float*)d_in[10];
  const float* Dv       = (const float*)d_in[11];
  const float* ssm_nw   = (const float*)d_in[12];
  const float* out_pw   = (const float*)d_in[13];
  const float* norm2_w  = (const float*)d_in[14];
  const float* norm2_b  = (const float*)d_in[15];
  const float* fc1_w    = (const float*)d_in[16];
  const float* fc1_b    = (const float*)d_in[17];
  const float* fc2_w    = (const float*)d_in[18];
  const float* fc2_b    = (const float*)d_in[19];
  const float* normf_w  = (const float*)d_in[20];
  const float* normf_b  = (const float*)d_in[21];
  float* out = (float*)d_out;

  float* ws = (float*)d_ws;
  const size_t NRES = 2*96*512;
  const size_t NHS  = (size_t)NROW*DM;
  const size_t NZX  = (size_t)NROW*ZD;
  const size_t NXBC = (size_t)NROW*CD;
  const size_t NDT  = (size_t)NROW*NH;
  const size_t NY   = (size_t)NROW*DI;
  const size_t NSB  = (size_t)NSEQ*4*NCH*192*16;  // 2359296
  float* res = ws;
  float* H   = res + NRES;
  float* R   = H + NHS;
  float* U   = R + NHS;
  float* ZX  = U + NHS;
  float* XBC = ZX + NZX;
  float* DT  = XBC + NXBC;
  float* DA  = DT + NDT;
  float* Y   = DA + NDT;
  float* YP3 = Y + NY;
  float* Sbuf= YP3 + 3*NY;
  float* Pbuf= Sbuf + NSB;
  float* T1  = XBC;             // alias: XBC dead once fc1 runs

  k_downsample<<<2*512, 128, 0, stream>>>(x, ds_ln_w, ds_ln_b, ds_red_w, res);
  k_build_hs<<<(NSEQ*LSEQ*DM + 255)/256, 256, 0, stream>>>(res, H);

  const int MB = NROW/64;   // 192
  const int SCB = NSEQ*4*NCH; // 768

  for (int l = 0; l < 2; l++){
    const float* n1w = norm1_w + l*DM,  * n1b = norm1_b + l*DM;
    const float* ipw = in_proj_w + (size_t)l*ZD*DM;
    const float* cw  = conv_w + (size_t)l*CD*4, * cb = conv_b + (size_t)l*CD;
    const float* dtb = dt_bias + l*NH, * alog = A_log + l*NH, * dvl = Dv + l*NH;
    const float* snw = ssm_nw + (size_t)l*DI;
    const float* opw = out_pw + (size_t)l*DM*DI;
    const float* n2w = norm2_w + l*DM,  * n2b = norm2_b + l*DM;
    const float* f1w = fc1_w + (size_t)l*DI*DM, * f1b = fc1_b + (size_t)l*DI;
    const float* f2w = fc2_w + (size_t)l*DM*DI, * f2b = fc2_b + (size_t)l*DM;

    k_add_ln<<<NROW, 128, 0, stream>>>(H, l == 0 ? nullptr : R, R, U, n1w, n1b);
    k_gemm_t<0><<<dim3(MB, 9), 256, 0, stream>>>(U, ipw, nullptr, ZX, ZD, DM, 0);
    k_conv4<<<(NSEQ*LSEQ*(CD/4) + 255)/256, 256, 0, stream>>>(ZX, cw, cb, XBC);
    k_dt<<<(NSEQ*LSEQ*NH + 255)/256, 256, 0, stream>>>(ZX, dtb, alog, DT, DA);
    k_scanA<<<SCB, 192, 0, stream>>>(XBC, DT, DA, Y, YP3, Sbuf, Pbuf);
    k_scanC<<<SCB, 192, 0, stream>>>(XBC, DA, Sbuf, Pbuf, Y, YP3);
    k_gate2<<<NROW, 192, 0, stream>>>(Y, YP3, XBC, ZX, dvl, snw);
    k_gemm_t<0><<<dim3(MB, 2), 256, 0, stream>>>(Y, opw, nullptr, R, DM, DI, 1);
    k_add_ln<<<NROW, 128, 0, stream>>>(R, nullptr, nullptr, U, n2w, n2b);
    k_gemm_t<1><<<dim3(MB, 3), 256, 0, stream>>>(U, f1w, f1b, T1, DI, DM, 0);
    k_gemm_t<0><<<dim3(MB, 2), 256, 0, stream>>>(T1, f2w, f2b, H, DM, DI, 0);
  }

  k_add_ln<<<NROW, 128, 0, stream>>>(H, R, nullptr, U, normf_w, normf_b);
  k_merge<<<(2*96*512 + 255)/256, 256, 0, stream>>>(U, out);
}